// Round 10
// baseline (155.880 us; speedup 1.0000x reference)
//
#include <hip/hip_runtime.h>

#define H     96    // hidden width of both MLPs
#define NOUT  32    // outputs of both MLPs
#define NSEG  97    // H+1 piecewise-linear segments
#define TPAD  128   // breakpoint array padded to pow2 for branchless search
#define TABQ  1552  // float4 per table (97*16)

#define NPB_LOG 6
#define NPB     64    // nodes per bucket
#define MAXBK   1600  // max buckets (N <= 102400)
#define EPB     2048  // edges per bucket_scatter block (782 blocks ~ 3/CU)
#define EPT     8     // edges per thread in bucket_scatter (EPB/256)
#define CAP     1536  // max bucket size for fast path (mean 1024, +16 sigma)
#define NP      2     // payloads staged per thread in bucket_gather

// ---- d_ws float-index layout -------------------------------------------
#define WS_TS_MSG   0          // float[128] sorted breakpoints (+inf pad)
#define WS_TS_SC    128        // float[128]
#define WS_ACS      256        // float2[97][32]  scalar (A, C+b2) [s][k]
#define WS_ACM      6464       // float4[97][16]  msg (A0,C0,A1,C1) [s][j]
#define WS_RANK     12672      // int[192]
#define WS_GBH      16384      // int[1600]  bucket sizes
#define WS_GBO      18048      // int[1600]  bucket offsets (excl scan)
#define WS_GCUR     19712      // int[1600]  bucket cursors
#define WS_PAY      21376      // float4[E]  bucket-grouped payloads

// ---------------------------------------------------------------------------
// P1: breakpoints t_j = -b1_j/w1_j, rank-sort, store sorted(+inf padded)+ranks
// ---------------------------------------------------------------------------
__global__ void build_breakpoints(const float* __restrict__ msg_w1,
                                  const float* __restrict__ msg_b1,
                                  const float* __restrict__ sc_w1,
                                  const float* __restrict__ sc_b1,
                                  float* __restrict__ ws) {
    __shared__ float t[2][H];
    const int tid = threadIdx.x;        // 192 threads
    const int mlp = tid / H;
    const int j   = tid % H;
    if (tid < 2 * H) {
        const float* w1 = mlp ? sc_w1 : msg_w1;
        const float* b1 = mlp ? sc_b1 : msg_b1;
        float w = w1[j], b = b1[j];
        t[mlp][j] = (w == 0.0f) ? __builtin_inff() : (-b / w);
    }
    __syncthreads();
    if (tid < 2 * H) {
        float tj = t[mlp][j];
        int r = 0;
        for (int i = 0; i < H; ++i) {
            float ti = t[mlp][i];
            r += (ti < tj) || (ti == tj && i < j);
        }
        float* ts = ws + (mlp ? WS_TS_SC : WS_TS_MSG);
        ts[r] = tj;
        ((int*)(ws + WS_RANK))[mlp * H + j] = r;
    }
    if (tid < 2 * (TPAD - H)) {
        int m2 = tid / (TPAD - H);
        int p  = tid % (TPAD - H);
        ws[m2 * TPAD + H + p] = __builtin_inff();
    }
}

// ---------------------------------------------------------------------------
// P2: per (segment, mlp): A,C with mlp(x) = A*x + C on that segment.
// ---------------------------------------------------------------------------
__global__ void build_tables(const float* __restrict__ msg_w1,
                             const float* __restrict__ msg_b1,
                             const float* __restrict__ msg_w2,
                             const float* __restrict__ msg_b2,
                             const float* __restrict__ sc_w1,
                             const float* __restrict__ sc_b1,
                             const float* __restrict__ sc_w2,
                             const float* __restrict__ sc_b2,
                             float* __restrict__ ws) {
    const int s   = blockIdx.x;   // 0..96
    const int mlp = blockIdx.y;   // 0 = msg, 1 = sc
    const int k   = threadIdx.x;  // 0..31
    const float* w1 = mlp ? sc_w1 : msg_w1;
    const float* b1 = mlp ? sc_b1 : msg_b1;
    const float* w2 = mlp ? sc_w2 : msg_w2;
    const float* b2 = mlp ? sc_b2 : msg_b2;
    const int* rank = (const int*)(ws + WS_RANK) + mlp * H;
    float A = 0.0f, C = 0.0f;
    for (int j = 0; j < H; ++j) {
        float w = w1[j], b = b1[j];
        int   r = rank[j];
        bool active = (w > 0.0f) ? (r < s)
                    : (w < 0.0f) ? (r >= s)
                                 : (b > 0.0f);
        if (active) {
            float wk = w2[j * NOUT + k];
            A = fmaf(w, wk, A);
            C = fmaf(b, wk, C);
        }
    }
    C += b2[k];
    if (mlp) {
        float* dst = ws + WS_ACS + 2 * (s * 32 + k);
        dst[0] = A; dst[1] = C;
    } else {
        float* dst = ws + WS_ACM + 4 * (s * 16 + (k >> 1)) + 2 * (k & 1);
        dst[0] = A; dst[1] = C;
    }
}

// ---------------------------------------------------------------------------
// K1: bucket histogram (LDS-privatized)
// ---------------------------------------------------------------------------
__global__ __launch_bounds__(256) void bucket_hist(
    const int* __restrict__ col, int* __restrict__ gbh, int E, int NBK)
{
    __shared__ int lcnt[MAXBK];
    for (int i = threadIdx.x; i < MAXBK; i += 256) lcnt[i] = 0;
    __syncthreads();
    for (int e = blockIdx.x * 256 + threadIdx.x; e < E; e += gridDim.x * 256)
        atomicAdd(&lcnt[col[e] >> NPB_LOG], 1);
    __syncthreads();
    for (int i = threadIdx.x; i < NBK; i += 256)
        if (lcnt[i]) atomicAdd(&gbh[i], lcnt[i]);
}

// ---------------------------------------------------------------------------
// K2: exclusive scan of bucket sizes (2 elems/thread -> up to 2048 buckets)
// ---------------------------------------------------------------------------
__global__ void scan_buckets(const int* __restrict__ gbh,
                             int* __restrict__ gbo, int* __restrict__ gcur,
                             int NBK) {
    __shared__ int sh[1024];
    int t = threadIdx.x;
    int i0 = 2 * t, i1 = 2 * t + 1;
    int a = (i0 < NBK) ? gbh[i0] : 0;
    int b = (i1 < NBK) ? gbh[i1] : 0;
    int s = a + b;
    sh[t] = s;
    __syncthreads();
    for (int off = 1; off < 1024; off <<= 1) {
        int u = (t >= off) ? sh[t - off] : 0;
        __syncthreads();
        sh[t] += u;
        __syncthreads();
    }
    int excl = sh[t] - s;
    if (i0 < NBK) { gbo[i0] = excl;     gcur[i0] = excl; }
    if (i1 < NBK) { gbo[i1] = excl + a; gcur[i1] = excl + a; }
}

// ---------------------------------------------------------------------------
// K3: bucket scatter. EPB=2048 -> 782 blocks (~3/CU). Each thread owns
// EPT=8 edges; col cached in registers across the two phases.
// payload = {x, sm | ss<<8 | (col&63)<<16, c, s}
// ---------------------------------------------------------------------------
__global__ __launch_bounds__(256) void bucket_scatter(
    const float* __restrict__ v, const float* __restrict__ rot,
    const int* __restrict__ col, const float* __restrict__ ws,
    int* __restrict__ gcur, float4* __restrict__ pay, int E, int NBK)
{
    __shared__ float ts_m[TPAD], ts_s[TPAD];
    __shared__ int lcnt[MAXBK], lbase[MAXBK];
    for (int i = threadIdx.x; i < 2 * TPAD; i += 256) {
        float val = ws[i];
        if (i < TPAD) ts_m[i] = val; else ts_s[i - TPAD] = val;
    }
    for (int i = threadIdx.x; i < MAXBK; i += 256) lcnt[i] = 0;
    __syncthreads();
    const int e0 = blockIdx.x * EPB;
    const int e1 = min(e0 + EPB, E);

    int col_r[EPT];
    #pragma unroll
    for (int i = 0; i < EPT; ++i) {
        int e = e0 + i * 256 + threadIdx.x;
        col_r[i] = (e < e1) ? col[e] : -1;
        if (col_r[i] >= 0) atomicAdd(&lcnt[col_r[i] >> NPB_LOG], 1);
    }
    __syncthreads();
    for (int b = threadIdx.x; b < NBK; b += 256) {
        int c = lcnt[b];
        lbase[b] = c ? atomicAdd(&gcur[b], c) : 0;
        lcnt[b] = 0;                       // reuse as cursor
    }
    __syncthreads();
    #pragma unroll
    for (int i = 0; i < EPT; ++i) {
        int e = e0 + i * 256 + threadIdx.x;
        int c = col_r[i];
        if (c < 0) continue;
        float2 vv = *(const float2*)(v + 2 * (size_t)e);
        float  x  = sqrtf(vv.x * vv.x + vv.y * vv.y);
        float4 r  = *(const float4*)(rot + 4 * (size_t)e);
        int sm = 0;
        #pragma unroll
        for (int st = 64; st > 0; st >>= 1) if (ts_m[sm + st - 1] < x) sm += st;
        int ss = 0;
        #pragma unroll
        for (int st = 64; st > 0; st >>= 1) if (ts_s[ss + st - 1] < x) ss += st;
        int b   = c >> NPB_LOG;
        int pos = lbase[b] + atomicAdd(&lcnt[b], 1);
        pay[pos] = make_float4(x,
            __int_as_float(sm | (ss << 8) | ((c & (NPB - 1)) << 16)),
            r.x, r.z);
    }
}

// ---------------------------------------------------------------------------
// K4+gather fused: block = bucket (64 nodes), 1024 threads = 16 waves.
// Phase A: reorder bucket payloads into LDS buf (node-sorted, CSR in LDS).
// Phase B: 128 node x mode tasks over 16 waves; R6-proven inner loop.
// LDS: 2 x 24832 (tables) + 24704 (buf) + 1 KB ctrl = 75.4 KB -> 2 blocks/CU.
// ---------------------------------------------------------------------------
__global__ __launch_bounds__(1024, 8) void bucket_gather(
    const float4* __restrict__ pay, const int* __restrict__ gbh,
    const int* __restrict__ gbo, const float* __restrict__ ws,
    float* __restrict__ out, int N)
{
    __shared__ float4 tabS[TABQ];        // scalar table, viewed as float2[3104]
    __shared__ float4 tabM[TABQ];        // msg table
    __shared__ float4 buf[CAP + 8];      // node-sorted payloads (+pad)
    __shared__ int s_cnt[NPB], s_scan[NPB], s_loff[NPB], s_cur[NPB];

    const int tid = threadIdx.x;
    const int b   = blockIdx.x;
    const int lo  = b << NPB_LOG;
    const int nn  = min(NPB, N - lo);
    const int bbeg = gbo[b];
    const int bsz  = gbh[b];

    {   // table load + buf zero-init (pk=0 -> safe table row 0 when guarded)
        const float4* srcS = (const float4*)(ws + WS_ACS);
        const float4* srcM = (const float4*)(ws + WS_ACM);
        for (int i = tid; i < TABQ; i += 1024) { tabS[i] = srcS[i]; tabM[i] = srcM[i]; }
        for (int i = tid; i < CAP + 8; i += 1024) buf[i] = make_float4(0.f, 0.f, 0.f, 0.f);
        if (tid < NPB) s_cnt[tid] = 0;
    }
    __syncthreads();

    if (bsz <= CAP) {
        // ---- Phase A: stage -> count -> scan -> reorder into buf ----
        float4 p[NP];
        int    loc[NP];
        #pragma unroll
        for (int i = 0; i < NP; ++i) {
            int idx = i * 1024 + tid;
            loc[i] = -1;
            if (idx < bsz) {
                p[i] = pay[bbeg + idx];
                loc[i] = (__float_as_int(p[i].y) >> 16) & (NPB - 1);
                atomicAdd(&s_cnt[loc[i]], 1);
            }
        }
        __syncthreads();
        if (tid < NPB) s_scan[tid] = s_cnt[tid];
        __syncthreads();
        for (int off = 1; off < NPB; off <<= 1) {
            int u = (tid < NPB && tid >= off) ? s_scan[tid - off] : 0;
            __syncthreads();
            if (tid < NPB) s_scan[tid] += u;
            __syncthreads();
        }
        if (tid < NPB) {
            s_loff[tid] = s_scan[tid] - s_cnt[tid];
            s_cur[tid]  = s_scan[tid] - s_cnt[tid];
        }
        __syncthreads();
        #pragma unroll
        for (int i = 0; i < NP; ++i) {
            if (loc[i] >= 0) {
                int pos = atomicAdd(&s_cur[loc[i]], 1);
                float4 q = p[i];
                q.y = __int_as_float(__float_as_int(q.y) & 0xFFFF);
                buf[pos] = q;
            }
        }
        __syncthreads();

        // ---- Phase B: 128 tasks (node x mode) over 16 waves ----
        const int wv   = tid >> 6;
        const int lane = tid & 63;
        const int k    = lane & 31;
        const int half = lane >> 5;
        const float2* t2 = (const float2*)tabS;
        const int jj = k >> 1, comp = k & 1;

        for (int i = 0; i < 8; ++i) {
            int task = wv + (i << 4);     // 0..127
            int mode = task >> NPB_LOG;
            int node = task & (NPB - 1);
            if (node >= nn) continue;
            int beg = s_loff[node];
            int cnt = s_cnt[node];
            float acc = 0.f, acc2 = 0.f;
            int tmax = (cnt + 1) >> 1;
            if (mode == 0) {
                int t = 0;
                for (; t + 2 <= tmax; t += 2) {
                    int e0 = 2 * t + half, e1 = e0 + 2;
                    float4 p0 = buf[beg + e0];
                    float4 p1 = buf[beg + e1];
                    float2 a0 = t2[(__float_as_int(p0.y) >> 8) * 32 + k];
                    float2 a1 = t2[(__float_as_int(p1.y) >> 8) * 32 + k];
                    float v0 = fmaf(a0.x, p0.x, a0.y);
                    float v1 = fmaf(a1.x, p1.x, a1.y);
                    acc  += (e0 < cnt) ? v0 : 0.f;
                    acc2 += (e1 < cnt) ? v1 : 0.f;
                }
                if (t < tmax) {
                    int e0 = 2 * t + half;
                    float4 p0 = buf[beg + e0];
                    float2 a0 = t2[(__float_as_int(p0.y) >> 8) * 32 + k];
                    float v0 = fmaf(a0.x, p0.x, a0.y);
                    acc += (e0 < cnt) ? v0 : 0.f;
                }
            } else {
                int t = 0;
                for (; t + 2 <= tmax; t += 2) {
                    int e0 = 2 * t + half, e1 = e0 + 2;
                    float4 p0 = buf[beg + e0];
                    float4 p1 = buf[beg + e1];
                    float4 a0 = tabM[(__float_as_int(p0.y) & 255) * 16 + jj];
                    float4 a1 = tabM[(__float_as_int(p1.y) & 255) * 16 + jj];
                    float m00 = fmaf(a0.x, p0.x, a0.y);
                    float m01 = fmaf(a0.z, p0.x, a0.w);
                    float m10 = fmaf(a1.x, p1.x, a1.y);
                    float m11 = fmaf(a1.z, p1.x, a1.w);
                    float v0 = comp ? fmaf(m01, p0.z, -(m00 * p0.w))
                                    : fmaf(m00, p0.z, m01 * p0.w);
                    float v1 = comp ? fmaf(m11, p1.z, -(m10 * p1.w))
                                    : fmaf(m10, p1.z, m11 * p1.w);
                    acc  += (e0 < cnt) ? v0 : 0.f;
                    acc2 += (e1 < cnt) ? v1 : 0.f;
                }
                if (t < tmax) {
                    int e0 = 2 * t + half;
                    float4 p0 = buf[beg + e0];
                    float4 a0 = tabM[(__float_as_int(p0.y) & 255) * 16 + jj];
                    float m00 = fmaf(a0.x, p0.x, a0.y);
                    float m01 = fmaf(a0.z, p0.x, a0.w);
                    float v0 = comp ? fmaf(m01, p0.z, -(m00 * p0.w))
                                    : fmaf(m00, p0.z, m01 * p0.w);
                    acc += (e0 < cnt) ? v0 : 0.f;
                }
            }
            acc += acc2;
            acc += __shfl_xor(acc, 32, 64);
            if (half == 0) {
                float* dst = out + (mode ? (size_t)N * 32 : 0)
                           + (size_t)(lo + node) * 32 + k;
                *dst = acc;
            }
        }
    } else {
        // ---- cold path (bsz > CAP, statistically unreachable): LDS accum ----
        float* accum = (float*)buf;   // [64][64]
        for (int i = tid; i < NPB * 64; i += 1024) accum[i] = 0.f;
        __syncthreads();
        const float2* t2 = (const float2*)tabS;
        for (int idx = tid; idx < bsz; idx += 1024) {
            float4 q = pay[bbeg + idx];
            int pk = __float_as_int(q.y);
            int node = (pk >> 16) & (NPB - 1);
            int sm = pk & 255, ss = (pk >> 8) & 255;
            float x = q.x, c = q.z, s = q.w;
            float* an = accum + node * 64;
            for (int kk = 0; kk < 32; ++kk) {
                float2 a = t2[ss * 32 + kk];
                atomicAdd(an + kk, fmaf(a.x, x, a.y));
            }
            for (int j2 = 0; j2 < 16; ++j2) {
                float4 a = tabM[sm * 16 + j2];
                float m0 = fmaf(a.x, x, a.y);
                float m1 = fmaf(a.z, x, a.w);
                atomicAdd(an + 32 + 2 * j2,     fmaf(m0, c, m1 * s));
                atomicAdd(an + 32 + 2 * j2 + 1, fmaf(m1, c, -(m0 * s)));
            }
        }
        __syncthreads();
        for (int i = tid; i < nn * 64; i += 1024) {
            int node = i >> 6, cc = i & 63;
            float* dst = out + ((cc < 32) ? 0 : (size_t)N * 32)
                       + (size_t)(lo + node) * 32 + (cc & 31);
            *dst = accum[node * 64 + cc];
        }
    }
}

extern "C" void kernel_launch(void* const* d_in, const int* in_sizes, int n_in,
                              void* d_out, int out_size, void* d_ws, size_t ws_size,
                              hipStream_t stream) {
    const float* v      = (const float*)d_in[0];
    const float* rot    = (const float*)d_in[1];
    const int*   ei     = (const int*)d_in[2];
    const float* msg_w1 = (const float*)d_in[3];
    const float* msg_b1 = (const float*)d_in[4];
    const float* msg_w2 = (const float*)d_in[5];
    const float* msg_b2 = (const float*)d_in[6];
    const float* sc_w1  = (const float*)d_in[7];
    const float* sc_b1  = (const float*)d_in[8];
    const float* sc_w2  = (const float*)d_in[9];
    const float* sc_b2  = (const float*)d_in[10];

    const int E = in_sizes[0] / 2;    // v is [E,2]
    const int N = out_size / 64;      // out = N*32 scalars + N*32 rot floats
    const int NBK = (N + NPB - 1) >> NPB_LOG;   // 1563 for N=100000

    float* ws  = (float*)d_ws;
    float* out = (float*)d_out;

    int*    gbh  = (int*)(ws + WS_GBH);
    int*    gbo  = (int*)(ws + WS_GBO);
    int*    gcur = (int*)(ws + WS_GCUR);
    float4* pay  = (float4*)(ws + WS_PAY);

    build_breakpoints<<<1, 192, 0, stream>>>(msg_w1, msg_b1, sc_w1, sc_b1, ws);
    build_tables<<<dim3(NSEG, 2), NOUT, 0, stream>>>(
        msg_w1, msg_b1, msg_w2, msg_b2, sc_w1, sc_b1, sc_w2, sc_b2, ws);

    hipMemsetAsync(gbh, 0, MAXBK * sizeof(int), stream);
    bucket_hist<<<256, 256, 0, stream>>>(ei + E, gbh, E, NBK);
    scan_buckets<<<1, 1024, 0, stream>>>(gbh, gbo, gcur, NBK);
    bucket_scatter<<<(E + EPB - 1) / EPB, 256, 0, stream>>>(
        v, rot, ei + E, ws, gcur, pay, E, NBK);
    bucket_gather<<<NBK, 1024, 0, stream>>>(pay, gbh, gbo, ws, out, N);
}

// Round 11
// 131.522 us; speedup vs baseline: 1.1852x; 1.1852x over previous
//
#include <hip/hip_runtime.h>
#include <hip/hip_fp16.h>

#define H     96    // hidden width of both MLPs
#define NOUT  32    // outputs of both MLPs
#define NSEG  97    // H+1 piecewise-linear segments
#define TPAD  128   // breakpoint array padded to pow2 for branchless search
#define TABQ  1552  // float4 per table (97*16)

#define NPB_LOG 6
#define NPB     64    // nodes per bucket
#define MAXBK   1600  // max buckets (N <= 102400)
#define EPB     4096  // edges per bucket_scatter block (391 blocks)
#define SCT     512   // scatter threads
#define EPT     8     // edges per thread in bucket_scatter (EPB/SCT)
#define CAP     1536  // max bucket size for gather fast path
#define NP      2     // payloads staged per thread in bucket_gather

// ---- d_ws float-index layout -------------------------------------------
#define WS_TS_MSG   0          // float[128] sorted msg breakpoints (+inf pad)
#define WS_TS_SC    128        // float[128] sorted sc breakpoints
#define WS_ACS      256        // float2[97][32]  scalar (A, C+b2) [s][k]
#define WS_ACM      6464       // float4[97][16]  msg (A0,C0,A1,C1) [s][j]
#define WS_RANK     12672      // int[192]
#define WS_TSQ      12864      // float[256] merged breakpoints (+inf pad)
#define WS_CNTM     13120      // int[256]  cnt_m[q] = #msg-breakpoints < q-th
#define WS_GBH      16384      // int[1600]  bucket sizes
#define WS_GBO      18048      // int[1600]  bucket offsets (excl scan)
#define WS_GCUR     19712      // int[1600]  bucket cursors
#define WS_PAY      21376      // uint2[E]   bucket-grouped 8B payloads

// ---------------------------------------------------------------------------
// P1: breakpoints t_j = -b1_j/w1_j; per-MLP rank sort AND merged rank sort.
// Merged array ts_q[256] (+inf pad) + prefix table cnt_m: for x in merged
// segment q, sm = cnt_m[q], ss = q - cnt_m[q].  One block, 256 threads.
// ---------------------------------------------------------------------------
__global__ void build_breakpoints(const float* __restrict__ msg_w1,
                                  const float* __restrict__ msg_b1,
                                  const float* __restrict__ sc_w1,
                                  const float* __restrict__ sc_b1,
                                  float* __restrict__ ws) {
    __shared__ float t[2][H];
    __shared__ int is_msg[256];
    const int tid = threadIdx.x;        // 256 threads
    const int mlp = tid / H;
    const int j   = tid % H;
    is_msg[tid] = 0;
    if (tid < 2 * H) {
        const float* w1 = mlp ? sc_w1 : msg_w1;
        const float* b1 = mlp ? sc_b1 : msg_b1;
        float w = w1[j], b = b1[j];
        t[mlp][j] = (w == 0.0f) ? __builtin_inff() : (-b / w);
    }
    __syncthreads();
    if (tid < 2 * H) {
        float tj = t[mlp][j];
        int r = 0;
        for (int i = 0; i < H; ++i) {
            float ti = t[mlp][i];
            r += (ti < tj) || (ti == tj && i < j);
        }
        float* ts = ws + (mlp ? WS_TS_SC : WS_TS_MSG);
        ts[r] = tj;
        ((int*)(ws + WS_RANK))[mlp * H + j] = r;
        // merged rank: msg elements precede sc elements on ties
        int cross = 0;
        if (mlp == 0) { for (int i = 0; i < H; ++i) cross += (t[1][i] <  tj); }
        else         { for (int i = 0; i < H; ++i) cross += (t[0][i] <= tj); }
        int q = r + cross;                 // 0..191, bijective
        ws[WS_TSQ + q] = tj;
        is_msg[q] = (mlp == 0);
    }
    if (tid < 2 * (TPAD - H)) {
        int m2 = tid / (TPAD - H);
        int p  = tid % (TPAD - H);
        ws[m2 * TPAD + H + p] = __builtin_inff();
    }
    if (tid < 64) ws[WS_TSQ + 192 + tid] = __builtin_inff();
    __syncthreads();
    if (tid == 0) {
        int acc = 0;
        int* cm = (int*)(ws + WS_CNTM);
        for (int i = 0; i < 256; ++i) { cm[i] = acc; acc += is_msg[i]; }
    }
}

// ---------------------------------------------------------------------------
// P2: per (segment, mlp): A,C with mlp(x) = A*x + C on that segment.
// ---------------------------------------------------------------------------
__global__ void build_tables(const float* __restrict__ msg_w1,
                             const float* __restrict__ msg_b1,
                             const float* __restrict__ msg_w2,
                             const float* __restrict__ msg_b2,
                             const float* __restrict__ sc_w1,
                             const float* __restrict__ sc_b1,
                             const float* __restrict__ sc_w2,
                             const float* __restrict__ sc_b2,
                             float* __restrict__ ws) {
    const int s   = blockIdx.x;   // 0..96
    const int mlp = blockIdx.y;   // 0 = msg, 1 = sc
    const int k   = threadIdx.x;  // 0..31
    const float* w1 = mlp ? sc_w1 : msg_w1;
    const float* b1 = mlp ? sc_b1 : msg_b1;
    const float* w2 = mlp ? sc_w2 : msg_w2;
    const float* b2 = mlp ? sc_b2 : msg_b2;
    const int* rank = (const int*)(ws + WS_RANK) + mlp * H;
    float A = 0.0f, C = 0.0f;
    for (int j = 0; j < H; ++j) {
        float w = w1[j], b = b1[j];
        int   r = rank[j];
        bool active = (w > 0.0f) ? (r < s)
                    : (w < 0.0f) ? (r >= s)
                                 : (b > 0.0f);
        if (active) {
            float wk = w2[j * NOUT + k];
            A = fmaf(w, wk, A);
            C = fmaf(b, wk, C);
        }
    }
    C += b2[k];
    if (mlp) {
        float* dst = ws + WS_ACS + 2 * (s * 32 + k);
        dst[0] = A; dst[1] = C;
    } else {
        float* dst = ws + WS_ACM + 4 * (s * 16 + (k >> 1)) + 2 * (k & 1);
        dst[0] = A; dst[1] = C;
    }
}

// ---------------------------------------------------------------------------
// K1: bucket histogram (LDS-privatized)
// ---------------------------------------------------------------------------
__global__ __launch_bounds__(256) void bucket_hist(
    const int* __restrict__ col, int* __restrict__ gbh, int E, int NBK)
{
    __shared__ int lcnt[MAXBK];
    for (int i = threadIdx.x; i < MAXBK; i += 256) lcnt[i] = 0;
    __syncthreads();
    for (int e = blockIdx.x * 256 + threadIdx.x; e < E; e += gridDim.x * 256)
        atomicAdd(&lcnt[col[e] >> NPB_LOG], 1);
    __syncthreads();
    for (int i = threadIdx.x; i < NBK; i += 256)
        if (lcnt[i]) atomicAdd(&gbh[i], lcnt[i]);
}

// ---------------------------------------------------------------------------
// K2: exclusive scan of bucket sizes (2 elems/thread -> up to 2048 buckets)
// ---------------------------------------------------------------------------
__global__ void scan_buckets(const int* __restrict__ gbh,
                             int* __restrict__ gbo, int* __restrict__ gcur,
                             int NBK) {
    __shared__ int sh[1024];
    int t = threadIdx.x;
    int i0 = 2 * t, i1 = 2 * t + 1;
    int a = (i0 < NBK) ? gbh[i0] : 0;
    int b = (i1 < NBK) ? gbh[i1] : 0;
    int s = a + b;
    sh[t] = s;
    __syncthreads();
    for (int off = 1; off < 1024; off <<= 1) {
        int u = (t >= off) ? sh[t - off] : 0;
        __syncthreads();
        sh[t] += u;
        __syncthreads();
    }
    int excl = sh[t] - s;
    if (i0 < NBK) { gbo[i0] = excl;     gcur[i0] = excl; }
    if (i1 < NBK) { gbo[i1] = excl + a; gcur[i1] = excl + a; }
}

// ---------------------------------------------------------------------------
// K3: bucket scatter, LDS-sorted coalesced writes, 8B payloads.
// payload: w0 = f16(x) | f16(c)<<16 ; w1 = f16(s) | q<<16 | (col&63)<<24
// Phases: count -> local scan (1600) -> global base -> insert into LDS
// bucket-sorted stage[] + gaddr[] -> streamed coalesced write-out.
// LDS ~= 70.6 KB -> 2 blocks/CU @ 512 threads.
// ---------------------------------------------------------------------------
__global__ __launch_bounds__(SCT) void bucket_scatter(
    const float* __restrict__ v, const float* __restrict__ rot,
    const int* __restrict__ col, const float* __restrict__ ws,
    int* __restrict__ gcur, uint2* __restrict__ pay, int E, int NBK)
{
    __shared__ float ts_q[256];
    __shared__ int   lcnt[MAXBK];     // counts -> reused as insert cursor
    __shared__ int   lofs[MAXBK];     // local exclusive offsets
    __shared__ int   gdelta[MAXBK];   // global_base - local_offset
    __shared__ int   sh[SCT];
    __shared__ uint2 stage[EPB];      // 32 KB
    __shared__ int   gaddr[EPB];      // 16 KB

    const int tid = threadIdx.x;
    for (int i = tid; i < 256; i += SCT) ts_q[i] = ws[WS_TSQ + i];
    for (int i = tid; i < MAXBK; i += SCT) lcnt[i] = 0;
    __syncthreads();

    const int e0 = blockIdx.x * EPB;
    const int e1 = min(e0 + EPB, E);

    // phase 1: count
    int col_r[EPT];
    #pragma unroll
    for (int i = 0; i < EPT; ++i) {
        int e = e0 + i * SCT + tid;
        col_r[i] = (e < e1) ? col[e] : -1;
        if (col_r[i] >= 0) atomicAdd(&lcnt[col_r[i] >> NPB_LOG], 1);
    }
    __syncthreads();

    // phase 2: local exclusive scan over MAXBK (4 buckets/thread + block scan)
    int b0 = tid * 4;
    int c0 = (b0 + 0 < MAXBK) ? lcnt[b0 + 0] : 0;
    int c1 = (b0 + 1 < MAXBK) ? lcnt[b0 + 1] : 0;
    int c2 = (b0 + 2 < MAXBK) ? lcnt[b0 + 2] : 0;
    int c3 = (b0 + 3 < MAXBK) ? lcnt[b0 + 3] : 0;
    int mysum = c0 + c1 + c2 + c3;
    sh[tid] = mysum;
    __syncthreads();
    for (int off = 1; off < SCT; off <<= 1) {
        int u = (tid >= off) ? sh[tid - off] : 0;
        __syncthreads();
        sh[tid] += u;
        __syncthreads();
    }
    {
        int run = sh[tid] - mysum;
        if (b0 + 0 < MAXBK) { lofs[b0 + 0] = run; run += c0; }
        if (b0 + 1 < MAXBK) { lofs[b0 + 1] = run; run += c1; }
        if (b0 + 2 < MAXBK) { lofs[b0 + 2] = run; run += c2; }
        if (b0 + 3 < MAXBK) { lofs[b0 + 3] = run; run += c3; }
    }
    __syncthreads();

    // phase 3: global base per touched bucket; reset lcnt as insert cursor
    for (int b = tid; b < NBK; b += SCT) {
        int c = lcnt[b];
        if (c) {
            int g = atomicAdd(&gcur[b], c);
            gdelta[b] = g - lofs[b];
        }
        lcnt[b] = lofs[b];
    }
    __syncthreads();

    // phase 4: compute payloads, insert bucket-sorted into LDS
    #pragma unroll
    for (int i = 0; i < EPT; ++i) {
        int e = e0 + i * SCT + tid;
        int c = col_r[i];
        if (c < 0) continue;
        float2 vv = *(const float2*)(v + 2 * (size_t)e);
        float  x  = sqrtf(vv.x * vv.x + vv.y * vv.y);
        float4 r  = *(const float4*)(rot + 4 * (size_t)e);
        int q = 0;
        #pragma unroll
        for (int st = 128; st > 0; st >>= 1)
            if (ts_q[q + st - 1] < x) q += st;
        unsigned hx = __half_as_ushort(__float2half(x));
        unsigned hc = __half_as_ushort(__float2half(r.x));
        unsigned hs = __half_as_ushort(__float2half(r.z));
        unsigned w0 = hx | (hc << 16);
        unsigned w1 = hs | ((unsigned)q << 16) | ((unsigned)(c & (NPB - 1)) << 24);
        int b    = c >> NPB_LOG;
        int lpos = atomicAdd(&lcnt[b], 1);
        stage[lpos] = make_uint2(w0, w1);
        gaddr[lpos] = gdelta[b] + lpos;
    }
    __syncthreads();

    // phase 5: streamed write-out (consecutive threads -> consecutive addrs)
    const int nB = e1 - e0;
    for (int i = tid; i < nB; i += SCT)
        pay[gaddr[i]] = stage[i];
}

// ---------------------------------------------------------------------------
// K4+gather fused: block = bucket (64 nodes), 1024 threads = 16 waves.
// Phase A: unpack 8B payloads (f16 -> f32, q -> sm,ss) into node-sorted LDS
// buf (float4 {x, pk, c, s}).  Phase B: UNCHANGED proven R9 inner loop.
// LDS ~= 76.4 KB -> 2 blocks/CU.
// ---------------------------------------------------------------------------
__global__ __launch_bounds__(1024, 8) void bucket_gather(
    const uint2* __restrict__ pay, const int* __restrict__ gbh,
    const int* __restrict__ gbo, const float* __restrict__ ws,
    float* __restrict__ out, int N)
{
    __shared__ float4 tabS[TABQ];        // scalar table, viewed as float2[3104]
    __shared__ float4 tabM[TABQ];        // msg table
    __shared__ float4 buf[CAP + 8];      // node-sorted payloads (+pad)
    __shared__ int cntm[256];
    __shared__ int s_cnt[NPB], s_scan[NPB], s_loff[NPB], s_cur[NPB];

    const int tid = threadIdx.x;
    const int b   = blockIdx.x;
    const int lo  = b << NPB_LOG;
    const int nn  = min(NPB, N - lo);
    const int bbeg = gbo[b];
    const int bsz  = gbh[b];

    {   // table load + buf zero-init (pk=0 -> safe table row 0 when guarded)
        const float4* srcS = (const float4*)(ws + WS_ACS);
        const float4* srcM = (const float4*)(ws + WS_ACM);
        for (int i = tid; i < TABQ; i += 1024) { tabS[i] = srcS[i]; tabM[i] = srcM[i]; }
        for (int i = tid; i < CAP + 8; i += 1024) buf[i] = make_float4(0.f, 0.f, 0.f, 0.f);
        if (tid < 256) cntm[tid] = ((const int*)(ws + WS_CNTM))[tid];
        if (tid < NPB) s_cnt[tid] = 0;
    }
    __syncthreads();

    if (bsz <= CAP) {
        // ---- Phase A: stage -> count -> scan -> unpack+reorder into buf ----
        uint2 p[NP];
        int   loc[NP];
        #pragma unroll
        for (int i = 0; i < NP; ++i) {
            int idx = i * 1024 + tid;
            loc[i] = -1;
            if (idx < bsz) {
                p[i] = pay[bbeg + idx];
                loc[i] = (p[i].y >> 24) & (NPB - 1);
                atomicAdd(&s_cnt[loc[i]], 1);
            }
        }
        __syncthreads();
        if (tid < NPB) s_scan[tid] = s_cnt[tid];
        __syncthreads();
        for (int off = 1; off < NPB; off <<= 1) {
            int u = (tid < NPB && tid >= off) ? s_scan[tid - off] : 0;
            __syncthreads();
            if (tid < NPB) s_scan[tid] += u;
            __syncthreads();
        }
        if (tid < NPB) {
            s_loff[tid] = s_scan[tid] - s_cnt[tid];
            s_cur[tid]  = s_scan[tid] - s_cnt[tid];
        }
        __syncthreads();
        #pragma unroll
        for (int i = 0; i < NP; ++i) {
            if (loc[i] >= 0) {
                int pos = atomicAdd(&s_cur[loc[i]], 1);
                int q  = (p[i].y >> 16) & 255;
                int sm = cntm[q];
                int ss = q - sm;
                float x = __half2float(__ushort_as_half((unsigned short)(p[i].x & 0xFFFF)));
                float c = __half2float(__ushort_as_half((unsigned short)(p[i].x >> 16)));
                float s = __half2float(__ushort_as_half((unsigned short)(p[i].y & 0xFFFF)));
                buf[pos] = make_float4(x, __int_as_float(sm | (ss << 8)), c, s);
            }
        }
        __syncthreads();

        // ---- Phase B: 128 tasks (node x mode) over 16 waves (R9-proven) ----
        const int wv   = tid >> 6;
        const int lane = tid & 63;
        const int k    = lane & 31;
        const int half = lane >> 5;
        const float2* t2 = (const float2*)tabS;
        const int jj = k >> 1, comp = k & 1;

        for (int i = 0; i < 8; ++i) {
            int task = wv + (i << 4);     // 0..127
            int mode = task >> NPB_LOG;
            int node = task & (NPB - 1);
            if (node >= nn) continue;
            int beg = s_loff[node];
            int cnt = s_cnt[node];
            float acc = 0.f, acc2 = 0.f;
            int tmax = (cnt + 1) >> 1;
            if (mode == 0) {
                int t = 0;
                for (; t + 2 <= tmax; t += 2) {
                    int e0 = 2 * t + half, e1 = e0 + 2;
                    float4 p0 = buf[beg + e0];
                    float4 p1 = buf[beg + e1];
                    float2 a0 = t2[(__float_as_int(p0.y) >> 8) * 32 + k];
                    float2 a1 = t2[(__float_as_int(p1.y) >> 8) * 32 + k];
                    float v0 = fmaf(a0.x, p0.x, a0.y);
                    float v1 = fmaf(a1.x, p1.x, a1.y);
                    acc  += (e0 < cnt) ? v0 : 0.f;
                    acc2 += (e1 < cnt) ? v1 : 0.f;
                }
                if (t < tmax) {
                    int e0 = 2 * t + half;
                    float4 p0 = buf[beg + e0];
                    float2 a0 = t2[(__float_as_int(p0.y) >> 8) * 32 + k];
                    float v0 = fmaf(a0.x, p0.x, a0.y);
                    acc += (e0 < cnt) ? v0 : 0.f;
                }
            } else {
                int t = 0;
                for (; t + 2 <= tmax; t += 2) {
                    int e0 = 2 * t + half, e1 = e0 + 2;
                    float4 p0 = buf[beg + e0];
                    float4 p1 = buf[beg + e1];
                    float4 a0 = tabM[(__float_as_int(p0.y) & 255) * 16 + jj];
                    float4 a1 = tabM[(__float_as_int(p1.y) & 255) * 16 + jj];
                    float m00 = fmaf(a0.x, p0.x, a0.y);
                    float m01 = fmaf(a0.z, p0.x, a0.w);
                    float m10 = fmaf(a1.x, p1.x, a1.y);
                    float m11 = fmaf(a1.z, p1.x, a1.w);
                    float v0 = comp ? fmaf(m01, p0.z, -(m00 * p0.w))
                                    : fmaf(m00, p0.z, m01 * p0.w);
                    float v1 = comp ? fmaf(m11, p1.z, -(m10 * p1.w))
                                    : fmaf(m10, p1.z, m11 * p1.w);
                    acc  += (e0 < cnt) ? v0 : 0.f;
                    acc2 += (e1 < cnt) ? v1 : 0.f;
                }
                if (t < tmax) {
                    int e0 = 2 * t + half;
                    float4 p0 = buf[beg + e0];
                    float4 a0 = tabM[(__float_as_int(p0.y) & 255) * 16 + jj];
                    float m00 = fmaf(a0.x, p0.x, a0.y);
                    float m01 = fmaf(a0.z, p0.x, a0.w);
                    float v0 = comp ? fmaf(m01, p0.z, -(m00 * p0.w))
                                    : fmaf(m00, p0.z, m01 * p0.w);
                    acc += (e0 < cnt) ? v0 : 0.f;
                }
            }
            acc += acc2;
            acc += __shfl_xor(acc, 32, 64);
            if (half == 0) {
                float* dst = out + (mode ? (size_t)N * 32 : 0)
                           + (size_t)(lo + node) * 32 + k;
                *dst = acc;
            }
        }
    } else {
        // ---- cold path (bsz > CAP, statistically unreachable): LDS accum ----
        float* accum = (float*)buf;   // [64][64]
        for (int i = tid; i < NPB * 64; i += 1024) accum[i] = 0.f;
        __syncthreads();
        const float2* t2 = (const float2*)tabS;
        for (int idx = tid; idx < bsz; idx += 1024) {
            uint2 qw = pay[bbeg + idx];
            int q  = (qw.y >> 16) & 255;
            int sm = cntm[q];
            int ss = q - sm;
            int node = (qw.y >> 24) & (NPB - 1);
            float x = __half2float(__ushort_as_half((unsigned short)(qw.x & 0xFFFF)));
            float c = __half2float(__ushort_as_half((unsigned short)(qw.x >> 16)));
            float s = __half2float(__ushort_as_half((unsigned short)(qw.y & 0xFFFF)));
            float* an = accum + node * 64;
            for (int kk = 0; kk < 32; ++kk) {
                float2 a = t2[ss * 32 + kk];
                atomicAdd(an + kk, fmaf(a.x, x, a.y));
            }
            for (int j2 = 0; j2 < 16; ++j2) {
                float4 a = tabM[sm * 16 + j2];
                float m0 = fmaf(a.x, x, a.y);
                float m1 = fmaf(a.z, x, a.w);
                atomicAdd(an + 32 + 2 * j2,     fmaf(m0, c, m1 * s));
                atomicAdd(an + 32 + 2 * j2 + 1, fmaf(m1, c, -(m0 * s)));
            }
        }
        __syncthreads();
        for (int i = tid; i < nn * 64; i += 1024) {
            int node = i >> 6, cc = i & 63;
            float* dst = out + ((cc < 32) ? 0 : (size_t)N * 32)
                       + (size_t)(lo + node) * 32 + (cc & 31);
            *dst = accum[node * 64 + cc];
        }
    }
}

extern "C" void kernel_launch(void* const* d_in, const int* in_sizes, int n_in,
                              void* d_out, int out_size, void* d_ws, size_t ws_size,
                              hipStream_t stream) {
    const float* v      = (const float*)d_in[0];
    const float* rot    = (const float*)d_in[1];
    const int*   ei     = (const int*)d_in[2];
    const float* msg_w1 = (const float*)d_in[3];
    const float* msg_b1 = (const float*)d_in[4];
    const float* msg_w2 = (const float*)d_in[5];
    const float* msg_b2 = (const float*)d_in[6];
    const float* sc_w1  = (const float*)d_in[7];
    const float* sc_b1  = (const float*)d_in[8];
    const float* sc_w2  = (const float*)d_in[9];
    const float* sc_b2  = (const float*)d_in[10];

    const int E = in_sizes[0] / 2;    // v is [E,2]
    const int N = out_size / 64;      // out = N*32 scalars + N*32 rot floats
    const int NBK = (N + NPB - 1) >> NPB_LOG;   // 1563 for N=100000

    float* ws  = (float*)d_ws;
    float* out = (float*)d_out;

    int*   gbh  = (int*)(ws + WS_GBH);
    int*   gbo  = (int*)(ws + WS_GBO);
    int*   gcur = (int*)(ws + WS_GCUR);
    uint2* pay  = (uint2*)(ws + WS_PAY);

    build_breakpoints<<<1, 256, 0, stream>>>(msg_w1, msg_b1, sc_w1, sc_b1, ws);
    build_tables<<<dim3(NSEG, 2), NOUT, 0, stream>>>(
        msg_w1, msg_b1, msg_w2, msg_b2, sc_w1, sc_b1, sc_w2, sc_b2, ws);

    hipMemsetAsync(gbh, 0, MAXBK * sizeof(int), stream);
    bucket_hist<<<256, 256, 0, stream>>>(ei + E, gbh, E, NBK);
    scan_buckets<<<1, 1024, 0, stream>>>(gbh, gbo, gcur, NBK);
    bucket_scatter<<<(E + EPB - 1) / EPB, SCT, 0, stream>>>(
        v, rot, ei + E, ws, gcur, pay, E, NBK);
    bucket_gather<<<NBK, 1024, 0, stream>>>(pay, gbh, gbo, ws, out, N);
}

// Round 12
// 124.618 us; speedup vs baseline: 1.2509x; 1.0554x over previous
//
#include <hip/hip_runtime.h>
#include <hip/hip_fp16.h>

#define H     96    // hidden width of both MLPs
#define NOUT  32    // outputs of both MLPs
#define NSEG  97    // H+1 piecewise-linear segments
#define SENTR 97    // all-zero sentinel table row
#define NROW  98
#define TPAD  128   // breakpoint array padded to pow2 for branchless search
#define TABQ  1568  // float4 per table (98*16)

#define NPB_LOG 6
#define NPB     64    // nodes per bucket
#define MAXBK   1600  // max buckets (N <= 102400)
#define EPB     4096  // edges per bucket_scatter block (391 blocks)
#define SCT     512   // scatter threads
#define EPT     8     // edges per thread in bucket_scatter (EPB/SCT)
#define CAP     1536  // max bucket size for gather fast path
#define BUFSZ   (CAP + NPB + 8)   // padded capacity
#define NP      2     // payloads staged per thread in bucket_gather

// prescaled sentinel pk: hi16 = 97*32, lo16 = 97*16
#define SENT_PK ((3104 << 16) | 1552)

// ---- d_ws float-index layout -------------------------------------------
#define WS_TS_MSG   0          // float[128] sorted msg breakpoints (+inf pad)
#define WS_TS_SC    128        // float[128] sorted sc breakpoints
#define WS_ACS      256        // float2[98][32]  scalar (A, C+b2) [s][k], row 97 = 0
#define WS_ACM      6528       // float4[98][16]  msg (A0,C0,A1,C1) [s][j], row 97 = 0
#define WS_RANK     12800      // int[192]
#define WS_TSQ      13056      // float[256] merged breakpoints (+inf pad)
#define WS_CNTM     13312      // int[256]  cnt_m[q] = #msg-breakpoints < q-th
#define WS_GBH      16384      // int[1600]  bucket sizes
#define WS_GBO      18048      // int[1600]  bucket offsets (excl scan)
#define WS_GCUR     19712      // int[1600]  bucket cursors
#define WS_PAY      21376      // uint2[E]   bucket-grouped 8B payloads

// ---------------------------------------------------------------------------
// P1: breakpoints t_j = -b1_j/w1_j; per-MLP rank sort AND merged rank sort.
// ---------------------------------------------------------------------------
__global__ void build_breakpoints(const float* __restrict__ msg_w1,
                                  const float* __restrict__ msg_b1,
                                  const float* __restrict__ sc_w1,
                                  const float* __restrict__ sc_b1,
                                  float* __restrict__ ws) {
    __shared__ float t[2][H];
    __shared__ int is_msg[256];
    const int tid = threadIdx.x;        // 256 threads
    const int mlp = tid / H;
    const int j   = tid % H;
    is_msg[tid] = 0;
    if (tid < 2 * H) {
        const float* w1 = mlp ? sc_w1 : msg_w1;
        const float* b1 = mlp ? sc_b1 : msg_b1;
        float w = w1[j], b = b1[j];
        t[mlp][j] = (w == 0.0f) ? __builtin_inff() : (-b / w);
    }
    __syncthreads();
    if (tid < 2 * H) {
        float tj = t[mlp][j];
        int r = 0;
        for (int i = 0; i < H; ++i) {
            float ti = t[mlp][i];
            r += (ti < tj) || (ti == tj && i < j);
        }
        float* ts = ws + (mlp ? WS_TS_SC : WS_TS_MSG);
        ts[r] = tj;
        ((int*)(ws + WS_RANK))[mlp * H + j] = r;
        int cross = 0;
        if (mlp == 0) { for (int i = 0; i < H; ++i) cross += (t[1][i] <  tj); }
        else         { for (int i = 0; i < H; ++i) cross += (t[0][i] <= tj); }
        int q = r + cross;                 // 0..191, bijective
        ws[WS_TSQ + q] = tj;
        is_msg[q] = (mlp == 0);
    }
    if (tid < 2 * (TPAD - H)) {
        int m2 = tid / (TPAD - H);
        int p  = tid % (TPAD - H);
        ws[m2 * TPAD + H + p] = __builtin_inff();
    }
    if (tid < 64) ws[WS_TSQ + 192 + tid] = __builtin_inff();
    __syncthreads();
    if (tid == 0) {
        int acc = 0;
        int* cm = (int*)(ws + WS_CNTM);
        for (int i = 0; i < 256; ++i) { cm[i] = acc; acc += is_msg[i]; }
    }
}

// ---------------------------------------------------------------------------
// P2: per (segment, mlp): A,C with mlp(x) = A*x + C. Row 97 = zero sentinel.
// ---------------------------------------------------------------------------
__global__ void build_tables(const float* __restrict__ msg_w1,
                             const float* __restrict__ msg_b1,
                             const float* __restrict__ msg_w2,
                             const float* __restrict__ msg_b2,
                             const float* __restrict__ sc_w1,
                             const float* __restrict__ sc_b1,
                             const float* __restrict__ sc_w2,
                             const float* __restrict__ sc_b2,
                             float* __restrict__ ws) {
    const int s   = blockIdx.x;   // 0..97
    const int mlp = blockIdx.y;   // 0 = msg, 1 = sc
    const int k   = threadIdx.x;  // 0..31
    float A = 0.0f, C = 0.0f;
    if (s != SENTR) {
        const float* w1 = mlp ? sc_w1 : msg_w1;
        const float* b1 = mlp ? sc_b1 : msg_b1;
        const float* w2 = mlp ? sc_w2 : msg_w2;
        const float* b2 = mlp ? sc_b2 : msg_b2;
        const int* rank = (const int*)(ws + WS_RANK) + mlp * H;
        for (int j = 0; j < H; ++j) {
            float w = w1[j], b = b1[j];
            int   r = rank[j];
            bool active = (w > 0.0f) ? (r < s)
                        : (w < 0.0f) ? (r >= s)
                                     : (b > 0.0f);
            if (active) {
                float wk = w2[j * NOUT + k];
                A = fmaf(w, wk, A);
                C = fmaf(b, wk, C);
            }
        }
        C += b2[k];
    }
    if (mlp) {
        float* dst = ws + WS_ACS + 2 * (s * 32 + k);
        dst[0] = A; dst[1] = C;
    } else {
        float* dst = ws + WS_ACM + 4 * (s * 16 + (k >> 1)) + 2 * (k & 1);
        dst[0] = A; dst[1] = C;
    }
}

// ---------------------------------------------------------------------------
// K1: bucket histogram (LDS-privatized)
// ---------------------------------------------------------------------------
__global__ __launch_bounds__(256) void bucket_hist(
    const int* __restrict__ col, int* __restrict__ gbh, int E, int NBK)
{
    __shared__ int lcnt[MAXBK];
    for (int i = threadIdx.x; i < MAXBK; i += 256) lcnt[i] = 0;
    __syncthreads();
    for (int e = blockIdx.x * 256 + threadIdx.x; e < E; e += gridDim.x * 256)
        atomicAdd(&lcnt[col[e] >> NPB_LOG], 1);
    __syncthreads();
    for (int i = threadIdx.x; i < NBK; i += 256)
        if (lcnt[i]) atomicAdd(&gbh[i], lcnt[i]);
}

// ---------------------------------------------------------------------------
// K2: exclusive scan of bucket sizes (2 elems/thread -> up to 2048 buckets)
// ---------------------------------------------------------------------------
__global__ void scan_buckets(const int* __restrict__ gbh,
                             int* __restrict__ gbo, int* __restrict__ gcur,
                             int NBK) {
    __shared__ int sh[1024];
    int t = threadIdx.x;
    int i0 = 2 * t, i1 = 2 * t + 1;
    int a = (i0 < NBK) ? gbh[i0] : 0;
    int b = (i1 < NBK) ? gbh[i1] : 0;
    int s = a + b;
    sh[t] = s;
    __syncthreads();
    for (int off = 1; off < 1024; off <<= 1) {
        int u = (t >= off) ? sh[t - off] : 0;
        __syncthreads();
        sh[t] += u;
        __syncthreads();
    }
    int excl = sh[t] - s;
    if (i0 < NBK) { gbo[i0] = excl;     gcur[i0] = excl; }
    if (i1 < NBK) { gbo[i1] = excl + a; gcur[i1] = excl + a; }
}

// ---------------------------------------------------------------------------
// K3: bucket scatter, LDS-sorted coalesced writes, 8B payloads (R11-proven).
// payload: w0 = f16(x) | f16(c)<<16 ; w1 = f16(s) | q<<16 | (col&63)<<24
// ---------------------------------------------------------------------------
__global__ __launch_bounds__(SCT) void bucket_scatter(
    const float* __restrict__ v, const float* __restrict__ rot,
    const int* __restrict__ col, const float* __restrict__ ws,
    int* __restrict__ gcur, uint2* __restrict__ pay, int E, int NBK)
{
    __shared__ float ts_q[256];
    __shared__ int   lcnt[MAXBK];     // counts -> reused as insert cursor
    __shared__ int   lofs[MAXBK];     // local exclusive offsets
    __shared__ int   gdelta[MAXBK];   // global_base - local_offset
    __shared__ int   sh[SCT];
    __shared__ uint2 stage[EPB];      // 32 KB
    __shared__ int   gaddr[EPB];      // 16 KB

    const int tid = threadIdx.x;
    for (int i = tid; i < 256; i += SCT) ts_q[i] = ws[WS_TSQ + i];
    for (int i = tid; i < MAXBK; i += SCT) lcnt[i] = 0;
    __syncthreads();

    const int e0 = blockIdx.x * EPB;
    const int e1 = min(e0 + EPB, E);

    // phase 1: count
    int col_r[EPT];
    #pragma unroll
    for (int i = 0; i < EPT; ++i) {
        int e = e0 + i * SCT + tid;
        col_r[i] = (e < e1) ? col[e] : -1;
        if (col_r[i] >= 0) atomicAdd(&lcnt[col_r[i] >> NPB_LOG], 1);
    }
    __syncthreads();

    // phase 2: local exclusive scan over MAXBK (4 buckets/thread + block scan)
    int b0 = tid * 4;
    int c0 = (b0 + 0 < MAXBK) ? lcnt[b0 + 0] : 0;
    int c1 = (b0 + 1 < MAXBK) ? lcnt[b0 + 1] : 0;
    int c2 = (b0 + 2 < MAXBK) ? lcnt[b0 + 2] : 0;
    int c3 = (b0 + 3 < MAXBK) ? lcnt[b0 + 3] : 0;
    int mysum = c0 + c1 + c2 + c3;
    sh[tid] = mysum;
    __syncthreads();
    for (int off = 1; off < SCT; off <<= 1) {
        int u = (tid >= off) ? sh[tid - off] : 0;
        __syncthreads();
        sh[tid] += u;
        __syncthreads();
    }
    {
        int run = sh[tid] - mysum;
        if (b0 + 0 < MAXBK) { lofs[b0 + 0] = run; run += c0; }
        if (b0 + 1 < MAXBK) { lofs[b0 + 1] = run; run += c1; }
        if (b0 + 2 < MAXBK) { lofs[b0 + 2] = run; run += c2; }
        if (b0 + 3 < MAXBK) { lofs[b0 + 3] = run; run += c3; }
    }
    __syncthreads();

    // phase 3: global base per touched bucket; reset lcnt as insert cursor
    for (int b = tid; b < NBK; b += SCT) {
        int c = lcnt[b];
        if (c) {
            int g = atomicAdd(&gcur[b], c);
            gdelta[b] = g - lofs[b];
        }
        lcnt[b] = lofs[b];
    }
    __syncthreads();

    // phase 4: compute payloads, insert bucket-sorted into LDS
    #pragma unroll
    for (int i = 0; i < EPT; ++i) {
        int e = e0 + i * SCT + tid;
        int c = col_r[i];
        if (c < 0) continue;
        float2 vv = *(const float2*)(v + 2 * (size_t)e);
        float  x  = sqrtf(vv.x * vv.x + vv.y * vv.y);
        float4 r  = *(const float4*)(rot + 4 * (size_t)e);
        int q = 0;
        #pragma unroll
        for (int st = 128; st > 0; st >>= 1)
            if (ts_q[q + st - 1] < x) q += st;
        unsigned hx = __half_as_ushort(__float2half(x));
        unsigned hc = __half_as_ushort(__float2half(r.x));
        unsigned hs = __half_as_ushort(__float2half(r.z));
        unsigned w0 = hx | (hc << 16);
        unsigned w1 = hs | ((unsigned)q << 16) | ((unsigned)(c & (NPB - 1)) << 24);
        int b    = c >> NPB_LOG;
        int lpos = atomicAdd(&lcnt[b], 1);
        stage[lpos] = make_uint2(w0, w1);
        gaddr[lpos] = gdelta[b] + lpos;
    }
    __syncthreads();

    // phase 5: streamed write-out (consecutive threads -> consecutive addrs)
    const int nB = e1 - e0;
    for (int i = tid; i < nB; i += SCT)
        pay[gaddr[i]] = stage[i];
}

// ---------------------------------------------------------------------------
// K4+gather fused: block = bucket (64 nodes), 1024 threads = 16 waves.
// Phase A: unpack 8B payloads into node-sorted buf with PRESCALED pk
// (hi16 = ss*32, lo16 = sm*16); runs pair-padded with zero-row-97 sentinel.
// Phase B: guard-free inner loop, dual acc chains, lshr/and+add indexing.
// LDS ~= 77 KB -> 2 blocks/CU.
// ---------------------------------------------------------------------------
__global__ __launch_bounds__(1024, 8) void bucket_gather(
    const uint2* __restrict__ pay, const int* __restrict__ gbh,
    const int* __restrict__ gbo, const float* __restrict__ ws,
    float* __restrict__ out, int N)
{
    __shared__ float4 tabS[TABQ];        // scalar, viewed as float2[98*32]
    __shared__ float4 tabM[TABQ];        // msg table
    __shared__ float4 buf[BUFSZ];        // node-sorted padded payloads
    __shared__ int cntm[256];
    __shared__ int s_cnt[NPB], s_loff[NPB], s_cur[NPB];

    const int tid = threadIdx.x;
    const int b   = blockIdx.x;
    const int lo  = b << NPB_LOG;
    const int nn  = min(NPB, N - lo);
    const int bbeg = gbo[b];
    const int bsz  = gbh[b];

    {
        const float4* srcS = (const float4*)(ws + WS_ACS);
        const float4* srcM = (const float4*)(ws + WS_ACM);
        for (int i = tid; i < TABQ; i += 1024) { tabS[i] = srcS[i]; tabM[i] = srcM[i]; }
        if (tid < 256) cntm[tid] = ((const int*)(ws + WS_CNTM))[tid];
        if (tid < NPB) s_cnt[tid] = 0;
    }
    __syncthreads();

    if (bsz <= CAP) {
        // ---- Phase A: stage -> count -> wave0 scan (padded) -> insert+pad ----
        uint2 p[NP];
        int   loc[NP];
        #pragma unroll
        for (int i = 0; i < NP; ++i) {
            int idx = i * 1024 + tid;
            loc[i] = -1;
            if (idx < bsz) {
                p[i] = pay[bbeg + idx];
                loc[i] = (p[i].y >> 24) & (NPB - 1);
                atomicAdd(&s_cnt[loc[i]], 1);
            }
        }
        __syncthreads();
        if (tid < 64) {
            int cnt = s_cnt[tid];
            int pc  = (cnt + 1) & ~1;          // pair-padded size
            int incl = pc;
            #pragma unroll
            for (int off = 1; off < 64; off <<= 1) {
                int u = __shfl_up(incl, off, 64);
                if (tid >= off) incl += u;
            }
            s_loff[tid] = incl - pc;
            s_cur[tid]  = incl - pc;
        }
        __syncthreads();
        #pragma unroll
        for (int i = 0; i < NP; ++i) {
            if (loc[i] >= 0) {
                int pos = atomicAdd(&s_cur[loc[i]], 1);
                int q  = (p[i].y >> 16) & 255;
                int sm = cntm[q];
                int ss = q - sm;
                float x = __half2float(__ushort_as_half((unsigned short)(p[i].x & 0xFFFF)));
                float c = __half2float(__ushort_as_half((unsigned short)(p[i].x >> 16)));
                float s = __half2float(__ushort_as_half((unsigned short)(p[i].y & 0xFFFF)));
                buf[pos] = make_float4(x,
                    __int_as_float(((ss << 5) << 16) | (sm << 4)), c, s);
            }
        }
        if (tid < NPB && (s_cnt[tid] & 1))
            buf[s_loff[tid] + s_cnt[tid]] =
                make_float4(0.f, __int_as_float(SENT_PK), 0.f, 0.f);
        __syncthreads();

        // ---- Phase B: 128 tasks (node x mode) over 16 waves, guard-free ----
        const int wv   = tid >> 6;
        const int lane = tid & 63;
        const int k    = lane & 31;
        const int half = lane >> 5;
        const float2* t2 = (const float2*)tabS;
        const int jj = k >> 1, comp = k & 1;

        for (int i = 0; i < 8; ++i) {
            int task = wv + (i << 4);     // 0..127
            int mode = task >> NPB_LOG;
            int node = task & (NPB - 1);
            if (node >= nn) continue;
            int beg  = s_loff[node];
            int tmax = (s_cnt[node] + 1) >> 1;   // complete pairs (padded)
            float acc = 0.f;
            if (mode == 0) {
                float a0c = 0.f, a1c = 0.f, acc0 = 0.f, acc1 = 0.f;
                int t = 0;
                for (; t + 2 <= tmax; t += 2) {
                    float4 p0 = buf[beg + 2 * t + half];
                    float4 p1 = buf[beg + 2 * t + 2 + half];
                    float2 a0 = t2[((unsigned)__float_as_int(p0.y) >> 16) + k];
                    float2 a1 = t2[((unsigned)__float_as_int(p1.y) >> 16) + k];
                    acc0 = fmaf(a0.x, p0.x, acc0); a0c += a0.y;
                    acc1 = fmaf(a1.x, p1.x, acc1); a1c += a1.y;
                }
                if (t < tmax) {
                    float4 p0 = buf[beg + 2 * t + half];
                    float2 a0 = t2[((unsigned)__float_as_int(p0.y) >> 16) + k];
                    acc0 = fmaf(a0.x, p0.x, acc0); a0c += a0.y;
                }
                acc = (acc0 + a0c) + (acc1 + a1c);
            } else {
                float acc0 = 0.f, b0 = 0.f, acc1 = 0.f, b1 = 0.f;
                int t = 0;
                for (; t + 2 <= tmax; t += 2) {
                    float4 p0 = buf[beg + 2 * t + half];
                    float4 p1 = buf[beg + 2 * t + 2 + half];
                    float4 a0 = tabM[(__float_as_int(p0.y) & 0xFFFF) + jj];
                    float4 a1 = tabM[(__float_as_int(p1.y) & 0xFFFF) + jj];
                    float m00 = fmaf(a0.x, p0.x, a0.y);
                    float m01 = fmaf(a0.z, p0.x, a0.w);
                    float m10 = fmaf(a1.x, p1.x, a1.y);
                    float m11 = fmaf(a1.z, p1.x, a1.w);
                    // even k: m0*c + m1*s ; odd k: m1*c - m0*s
                    float u0 = comp ? -p0.w : p0.z, w0 = comp ? p0.z : p0.w;
                    float u1 = comp ? -p1.w : p1.z, w1 = comp ? p1.z : p1.w;
                    acc0 = fmaf(m00, u0, acc0);
                    b0   = fmaf(m01, w0, b0);
                    acc1 = fmaf(m10, u1, acc1);
                    b1   = fmaf(m11, w1, b1);
                }
                if (t < tmax) {
                    float4 p0 = buf[beg + 2 * t + half];
                    float4 a0 = tabM[(__float_as_int(p0.y) & 0xFFFF) + jj];
                    float m00 = fmaf(a0.x, p0.x, a0.y);
                    float m01 = fmaf(a0.z, p0.x, a0.w);
                    float u0 = comp ? -p0.w : p0.z, w0 = comp ? p0.z : p0.w;
                    acc0 = fmaf(m00, u0, acc0);
                    b0   = fmaf(m01, w0, b0);
                }
                acc = (acc0 + b0) + (acc1 + b1);
            }
            acc += __shfl_xor(acc, 32, 64);
            if (half == 0) {
                float* dst = out + (mode ? (size_t)N * 32 : 0)
                           + (size_t)(lo + node) * 32 + k;
                *dst = acc;
            }
        }
    } else {
        // ---- cold path (bsz > CAP, statistically unreachable): LDS accum ----
        float* accum = (float*)buf;   // [64][64]
        for (int i = tid; i < NPB * 64; i += 1024) accum[i] = 0.f;
        __syncthreads();
        const float2* t2 = (const float2*)tabS;
        for (int idx = tid; idx < bsz; idx += 1024) {
            uint2 qw = pay[bbeg + idx];
            int q  = (qw.y >> 16) & 255;
            int sm = cntm[q];
            int ss = q - sm;
            int node = (qw.y >> 24) & (NPB - 1);
            float x = __half2float(__ushort_as_half((unsigned short)(qw.x & 0xFFFF)));
            float c = __half2float(__ushort_as_half((unsigned short)(qw.x >> 16)));
            float s = __half2float(__ushort_as_half((unsigned short)(qw.y & 0xFFFF)));
            float* an = accum + node * 64;
            for (int kk = 0; kk < 32; ++kk) {
                float2 a = t2[ss * 32 + kk];
                atomicAdd(an + kk, fmaf(a.x, x, a.y));
            }
            for (int j2 = 0; j2 < 16; ++j2) {
                float4 a = tabM[sm * 16 + j2];
                float m0 = fmaf(a.x, x, a.y);
                float m1 = fmaf(a.z, x, a.w);
                atomicAdd(an + 32 + 2 * j2,     fmaf(m0, c, m1 * s));
                atomicAdd(an + 32 + 2 * j2 + 1, fmaf(m1, c, -(m0 * s)));
            }
        }
        __syncthreads();
        for (int i = tid; i < nn * 64; i += 1024) {
            int node = i >> 6, cc = i & 63;
            float* dst = out + ((cc < 32) ? 0 : (size_t)N * 32)
                       + (size_t)(lo + node) * 32 + (cc & 31);
            *dst = accum[node * 64 + cc];
        }
    }
}

extern "C" void kernel_launch(void* const* d_in, const int* in_sizes, int n_in,
                              void* d_out, int out_size, void* d_ws, size_t ws_size,
                              hipStream_t stream) {
    const float* v      = (const float*)d_in[0];
    const float* rot    = (const float*)d_in[1];
    const int*   ei     = (const int*)d_in[2];
    const float* msg_w1 = (const float*)d_in[3];
    const float* msg_b1 = (const float*)d_in[4];
    const float* msg_w2 = (const float*)d_in[5];
    const float* msg_b2 = (const float*)d_in[6];
    const float* sc_w1  = (const float*)d_in[7];
    const float* sc_b1  = (const float*)d_in[8];
    const float* sc_w2  = (const float*)d_in[9];
    const float* sc_b2  = (const float*)d_in[10];

    const int E = in_sizes[0] / 2;    // v is [E,2]
    const int N = out_size / 64;      // out = N*32 scalars + N*32 rot floats
    const int NBK = (N + NPB - 1) >> NPB_LOG;   // 1563 for N=100000

    float* ws  = (float*)d_ws;
    float* out = (float*)d_out;

    int*   gbh  = (int*)(ws + WS_GBH);
    int*   gbo  = (int*)(ws + WS_GBO);
    int*   gcur = (int*)(ws + WS_GCUR);
    uint2* pay  = (uint2*)(ws + WS_PAY);

    build_breakpoints<<<1, 256, 0, stream>>>(msg_w1, msg_b1, sc_w1, sc_b1, ws);
    build_tables<<<dim3(NROW, 2), NOUT, 0, stream>>>(
        msg_w1, msg_b1, msg_w2, msg_b2, sc_w1, sc_b1, sc_w2, sc_b2, ws);

    hipMemsetAsync(gbh, 0, MAXBK * sizeof(int), stream);
    bucket_hist<<<256, 256, 0, stream>>>(ei + E, gbh, E, NBK);
    scan_buckets<<<1, 1024, 0, stream>>>(gbh, gbo, gcur, NBK);
    bucket_scatter<<<(E + EPB - 1) / EPB, SCT, 0, stream>>>(
        v, rot, ei + E, ws, gcur, pay, E, NBK);
    bucket_gather<<<NBK, 1024, 0, stream>>>(pay, gbh, gbo, ws, out, N);
}

// Round 13
// 109.486 us; speedup vs baseline: 1.4237x; 1.1382x over previous
//
#include <hip/hip_runtime.h>
#include <hip/hip_fp16.h>

#define H     96    // hidden width of both MLPs
#define NOUT  32    // outputs of both MLPs
#define NSEG  97    // H+1 piecewise-linear segments
#define SENTR 97    // all-zero sentinel table row
#define NROW  98
#define TPAD  128   // breakpoint array padded to pow2 for branchless search
#define TABQ  1568  // float4 per table (98*16)

#define NPB_LOG 6
#define NPB     64    // nodes per bucket
#define MAXBK   1600  // max buckets (N <= 102400)
#define EPB     4096  // edges per bucket_scatter block (391 blocks)
#define SCT     512   // scatter threads
#define EPT     8     // edges per thread in bucket_scatter (EPB/SCT)
#define CAP     1536  // fixed bucket region stride (mean 1024, +16 sigma)
#define BUFSZ   (CAP + NPB + 8)   // padded gather buffer capacity
#define NP      2     // payloads staged per thread in bucket_gather

// prescaled sentinel pk: hi16 = 97*32, lo16 = 97*16
#define SENT_PK ((3104 << 16) | 1552)

// ---- d_ws float-index layout -------------------------------------------
#define WS_TS_MSG   0          // float[128] sorted msg breakpoints (+inf pad)
#define WS_TS_SC    128        // float[128] sorted sc breakpoints
#define WS_ACS      256        // float2[98][32]  scalar (A, C+b2) [s][k], row 97 = 0
#define WS_ACM      6528       // float4[98][16]  msg (A0,C0,A1,C1) [s][j], row 97 = 0
#define WS_RANK     12800      // int[192]
#define WS_TSQ      13056      // float[256] merged breakpoints (+inf pad)
#define WS_CNTM     13312      // int[256]  cnt_m[q] = #msg-breakpoints < q-th
#define WS_GCUR     16384      // int[1600]  bucket cursors (counts after scatter)
#define WS_PAY      18048      // uint2[NBK*CAP + 1]  fixed-stride bucket payloads

// ---------------------------------------------------------------------------
// P1: breakpoints t_j = -b1_j/w1_j; per-MLP rank sort AND merged rank sort.
// ---------------------------------------------------------------------------
__global__ void build_breakpoints(const float* __restrict__ msg_w1,
                                  const float* __restrict__ msg_b1,
                                  const float* __restrict__ sc_w1,
                                  const float* __restrict__ sc_b1,
                                  float* __restrict__ ws) {
    __shared__ float t[2][H];
    __shared__ int is_msg[256];
    const int tid = threadIdx.x;        // 256 threads
    const int mlp = tid / H;
    const int j   = tid % H;
    is_msg[tid] = 0;
    if (tid < 2 * H) {
        const float* w1 = mlp ? sc_w1 : msg_w1;
        const float* b1 = mlp ? sc_b1 : msg_b1;
        float w = w1[j], b = b1[j];
        t[mlp][j] = (w == 0.0f) ? __builtin_inff() : (-b / w);
    }
    __syncthreads();
    if (tid < 2 * H) {
        float tj = t[mlp][j];
        int r = 0;
        for (int i = 0; i < H; ++i) {
            float ti = t[mlp][i];
            r += (ti < tj) || (ti == tj && i < j);
        }
        float* ts = ws + (mlp ? WS_TS_SC : WS_TS_MSG);
        ts[r] = tj;
        ((int*)(ws + WS_RANK))[mlp * H + j] = r;
        int cross = 0;
        if (mlp == 0) { for (int i = 0; i < H; ++i) cross += (t[1][i] <  tj); }
        else         { for (int i = 0; i < H; ++i) cross += (t[0][i] <= tj); }
        int q = r + cross;                 // 0..191, bijective
        ws[WS_TSQ + q] = tj;
        is_msg[q] = (mlp == 0);
    }
    if (tid < 2 * (TPAD - H)) {
        int m2 = tid / (TPAD - H);
        int p  = tid % (TPAD - H);
        ws[m2 * TPAD + H + p] = __builtin_inff();
    }
    if (tid < 64) ws[WS_TSQ + 192 + tid] = __builtin_inff();
    __syncthreads();
    if (tid == 0) {
        int acc = 0;
        int* cm = (int*)(ws + WS_CNTM);
        for (int i = 0; i < 256; ++i) { cm[i] = acc; acc += is_msg[i]; }
    }
}

// ---------------------------------------------------------------------------
// P2: per (segment, mlp): A,C with mlp(x) = A*x + C. Row 97 = zero sentinel.
// ---------------------------------------------------------------------------
__global__ void build_tables(const float* __restrict__ msg_w1,
                             const float* __restrict__ msg_b1,
                             const float* __restrict__ msg_w2,
                             const float* __restrict__ msg_b2,
                             const float* __restrict__ sc_w1,
                             const float* __restrict__ sc_b1,
                             const float* __restrict__ sc_w2,
                             const float* __restrict__ sc_b2,
                             float* __restrict__ ws) {
    const int s   = blockIdx.x;   // 0..97
    const int mlp = blockIdx.y;   // 0 = msg, 1 = sc
    const int k   = threadIdx.x;  // 0..31
    float A = 0.0f, C = 0.0f;
    if (s != SENTR) {
        const float* w1 = mlp ? sc_w1 : msg_w1;
        const float* b1 = mlp ? sc_b1 : msg_b1;
        const float* w2 = mlp ? sc_w2 : msg_w2;
        const float* b2 = mlp ? sc_b2 : msg_b2;
        const int* rank = (const int*)(ws + WS_RANK) + mlp * H;
        for (int j = 0; j < H; ++j) {
            float w = w1[j], b = b1[j];
            int   r = rank[j];
            bool active = (w > 0.0f) ? (r < s)
                        : (w < 0.0f) ? (r >= s)
                                     : (b > 0.0f);
            if (active) {
                float wk = w2[j * NOUT + k];
                A = fmaf(w, wk, A);
                C = fmaf(b, wk, C);
            }
        }
        C += b2[k];
    }
    if (mlp) {
        float* dst = ws + WS_ACS + 2 * (s * 32 + k);
        dst[0] = A; dst[1] = C;
    } else {
        float* dst = ws + WS_ACM + 4 * (s * 16 + (k >> 1)) + 2 * (k & 1);
        dst[0] = A; dst[1] = C;
    }
}

// ---------------------------------------------------------------------------
// K3: bucket scatter into FIXED-STRIDE bucket regions (pay[b*CAP + i]).
// No hist/scan needed: global base = b*CAP + atomicAdd(gcur[b], c).
// LDS-sorted coalesced writes, 8B payloads (R11/R12-proven structure).
// payload: w0 = f16(x) | f16(c)<<16 ; w1 = f16(s) | q<<16 | (col&63)<<24
// ---------------------------------------------------------------------------
__global__ __launch_bounds__(SCT) void bucket_scatter(
    const float* __restrict__ v, const float* __restrict__ rot,
    const int* __restrict__ col, const float* __restrict__ ws,
    int* __restrict__ gcur, uint2* __restrict__ pay, int E, int NBK)
{
    __shared__ float ts_q[256];
    __shared__ int   lcnt[MAXBK];     // counts -> reused as insert cursor
    __shared__ int   lofs[MAXBK];     // local exclusive offsets
    __shared__ int   gdelta[MAXBK];   // b*CAP + global_base - local_offset
    __shared__ int   sh[SCT];
    __shared__ uint2 stage[EPB];      // 32 KB
    __shared__ int   gaddr[EPB];      // 16 KB

    const int tid = threadIdx.x;
    for (int i = tid; i < 256; i += SCT) ts_q[i] = ws[WS_TSQ + i];
    for (int i = tid; i < MAXBK; i += SCT) lcnt[i] = 0;
    __syncthreads();

    const int e0 = blockIdx.x * EPB;
    const int e1 = min(e0 + EPB, E);
    const int DUMP = NBK * CAP;       // spare slot for (unreachable) overflow

    // phase 1: count
    int col_r[EPT];
    #pragma unroll
    for (int i = 0; i < EPT; ++i) {
        int e = e0 + i * SCT + tid;
        col_r[i] = (e < e1) ? col[e] : -1;
        if (col_r[i] >= 0) atomicAdd(&lcnt[col_r[i] >> NPB_LOG], 1);
    }
    __syncthreads();

    // phase 2: local exclusive scan over MAXBK (4 buckets/thread + block scan)
    int b0 = tid * 4;
    int c0 = (b0 + 0 < MAXBK) ? lcnt[b0 + 0] : 0;
    int c1 = (b0 + 1 < MAXBK) ? lcnt[b0 + 1] : 0;
    int c2 = (b0 + 2 < MAXBK) ? lcnt[b0 + 2] : 0;
    int c3 = (b0 + 3 < MAXBK) ? lcnt[b0 + 3] : 0;
    int mysum = c0 + c1 + c2 + c3;
    sh[tid] = mysum;
    __syncthreads();
    for (int off = 1; off < SCT; off <<= 1) {
        int u = (tid >= off) ? sh[tid - off] : 0;
        __syncthreads();
        sh[tid] += u;
        __syncthreads();
    }
    {
        int run = sh[tid] - mysum;
        if (b0 + 0 < MAXBK) { lofs[b0 + 0] = run; run += c0; }
        if (b0 + 1 < MAXBK) { lofs[b0 + 1] = run; run += c1; }
        if (b0 + 2 < MAXBK) { lofs[b0 + 2] = run; run += c2; }
        if (b0 + 3 < MAXBK) { lofs[b0 + 3] = run; run += c3; }
    }
    __syncthreads();

    // phase 3: per-bucket global base from fixed-stride region
    for (int b = tid; b < NBK; b += SCT) {
        int c = lcnt[b];
        if (c) {
            int g = atomicAdd(&gcur[b], c);
            gdelta[b] = b * CAP + g - lofs[b];
        }
        lcnt[b] = lofs[b];            // reuse as insert cursor
    }
    __syncthreads();

    // phase 4: compute payloads, insert bucket-sorted into LDS
    #pragma unroll
    for (int i = 0; i < EPT; ++i) {
        int e = e0 + i * SCT + tid;
        int c = col_r[i];
        if (c < 0) continue;
        float2 vv = *(const float2*)(v + 2 * (size_t)e);
        float  x  = sqrtf(vv.x * vv.x + vv.y * vv.y);
        float4 r  = *(const float4*)(rot + 4 * (size_t)e);
        int q = 0;
        #pragma unroll
        for (int st = 128; st > 0; st >>= 1)
            if (ts_q[q + st - 1] < x) q += st;
        unsigned hx = __half_as_ushort(__float2half(x));
        unsigned hc = __half_as_ushort(__float2half(r.x));
        unsigned hs = __half_as_ushort(__float2half(r.z));
        unsigned w0 = hx | (hc << 16);
        unsigned w1 = hs | ((unsigned)q << 16) | ((unsigned)(c & (NPB - 1)) << 24);
        int b    = c >> NPB_LOG;
        int lpos = atomicAdd(&lcnt[b], 1);
        int abspos = gdelta[b] + lpos;
        stage[lpos] = make_uint2(w0, w1);
        gaddr[lpos] = (abspos - b * CAP < CAP) ? abspos : DUMP;
    }
    __syncthreads();

    // phase 5: streamed write-out (consecutive threads -> consecutive addrs)
    const int nB = e1 - e0;
    for (int i = tid; i < nB; i += SCT)
        pay[gaddr[i]] = stage[i];
}

// ---------------------------------------------------------------------------
// K4+gather fused: block = bucket (64 nodes), 1024 threads = 16 waves.
// Reads bucket size from gcur[b], base = b*CAP (no gbh/gbo).
// Phase A: unpack 8B payloads into node-sorted buf with prescaled pk;
// runs pair-padded with zero-row-97 sentinel.  Phase B: R12-proven loop.
// ---------------------------------------------------------------------------
__global__ __launch_bounds__(1024, 8) void bucket_gather(
    const uint2* __restrict__ pay, const int* __restrict__ gcur,
    const float* __restrict__ ws, float* __restrict__ out, int N)
{
    __shared__ float4 tabS[TABQ];        // scalar, viewed as float2[98*32]
    __shared__ float4 tabM[TABQ];        // msg table
    __shared__ float4 buf[BUFSZ];        // node-sorted padded payloads
    __shared__ int cntm[256];
    __shared__ int s_cnt[NPB], s_loff[NPB], s_cur[NPB];

    const int tid = threadIdx.x;
    const int b   = blockIdx.x;
    const int lo  = b << NPB_LOG;
    const int nn  = min(NPB, N - lo);
    const int bbeg = b * CAP;
    const int bsz  = min(gcur[b], CAP);

    {
        const float4* srcS = (const float4*)(ws + WS_ACS);
        const float4* srcM = (const float4*)(ws + WS_ACM);
        for (int i = tid; i < TABQ; i += 1024) { tabS[i] = srcS[i]; tabM[i] = srcM[i]; }
        if (tid < 256) cntm[tid] = ((const int*)(ws + WS_CNTM))[tid];
        if (tid < NPB) s_cnt[tid] = 0;
    }
    __syncthreads();

    // ---- Phase A: stage -> count -> wave0 scan (padded) -> insert+pad ----
    uint2 p[NP];
    int   loc[NP];
    #pragma unroll
    for (int i = 0; i < NP; ++i) {
        int idx = i * 1024 + tid;
        loc[i] = -1;
        if (idx < bsz) {
            p[i] = pay[bbeg + idx];
            loc[i] = (p[i].y >> 24) & (NPB - 1);
            atomicAdd(&s_cnt[loc[i]], 1);
        }
    }
    __syncthreads();
    if (tid < 64) {
        int cnt = s_cnt[tid];
        int pc  = (cnt + 1) & ~1;          // pair-padded size
        int incl = pc;
        #pragma unroll
        for (int off = 1; off < 64; off <<= 1) {
            int u = __shfl_up(incl, off, 64);
            if (tid >= off) incl += u;
        }
        s_loff[tid] = incl - pc;
        s_cur[tid]  = incl - pc;
    }
    __syncthreads();
    #pragma unroll
    for (int i = 0; i < NP; ++i) {
        if (loc[i] >= 0) {
            int pos = atomicAdd(&s_cur[loc[i]], 1);
            int q  = (p[i].y >> 16) & 255;
            int sm = cntm[q];
            int ss = q - sm;
            float x = __half2float(__ushort_as_half((unsigned short)(p[i].x & 0xFFFF)));
            float c = __half2float(__ushort_as_half((unsigned short)(p[i].x >> 16)));
            float s = __half2float(__ushort_as_half((unsigned short)(p[i].y & 0xFFFF)));
            buf[pos] = make_float4(x,
                __int_as_float(((ss << 5) << 16) | (sm << 4)), c, s);
        }
    }
    if (tid < NPB && (s_cnt[tid] & 1))
        buf[s_loff[tid] + s_cnt[tid]] =
            make_float4(0.f, __int_as_float(SENT_PK), 0.f, 0.f);
    __syncthreads();

    // ---- Phase B: 128 tasks (node x mode) over 16 waves, guard-free ----
    const int wv   = tid >> 6;
    const int lane = tid & 63;
    const int k    = lane & 31;
    const int half = lane >> 5;
    const float2* t2 = (const float2*)tabS;
    const int jj = k >> 1, comp = k & 1;

    for (int i = 0; i < 8; ++i) {
        int task = wv + (i << 4);     // 0..127
        int mode = task >> NPB_LOG;
        int node = task & (NPB - 1);
        if (node >= nn) continue;
        int beg  = s_loff[node];
        int tmax = (s_cnt[node] + 1) >> 1;   // complete pairs (padded)
        float acc = 0.f;
        if (mode == 0) {
            float a0c = 0.f, a1c = 0.f, acc0 = 0.f, acc1 = 0.f;
            int t = 0;
            for (; t + 2 <= tmax; t += 2) {
                float4 p0 = buf[beg + 2 * t + half];
                float4 p1 = buf[beg + 2 * t + 2 + half];
                float2 a0 = t2[((unsigned)__float_as_int(p0.y) >> 16) + k];
                float2 a1 = t2[((unsigned)__float_as_int(p1.y) >> 16) + k];
                acc0 = fmaf(a0.x, p0.x, acc0); a0c += a0.y;
                acc1 = fmaf(a1.x, p1.x, acc1); a1c += a1.y;
            }
            if (t < tmax) {
                float4 p0 = buf[beg + 2 * t + half];
                float2 a0 = t2[((unsigned)__float_as_int(p0.y) >> 16) + k];
                acc0 = fmaf(a0.x, p0.x, acc0); a0c += a0.y;
            }
            acc = (acc0 + a0c) + (acc1 + a1c);
        } else {
            float acc0 = 0.f, b0 = 0.f, acc1 = 0.f, b1 = 0.f;
            int t = 0;
            for (; t + 2 <= tmax; t += 2) {
                float4 p0 = buf[beg + 2 * t + half];
                float4 p1 = buf[beg + 2 * t + 2 + half];
                float4 a0 = tabM[(__float_as_int(p0.y) & 0xFFFF) + jj];
                float4 a1 = tabM[(__float_as_int(p1.y) & 0xFFFF) + jj];
                float m00 = fmaf(a0.x, p0.x, a0.y);
                float m01 = fmaf(a0.z, p0.x, a0.w);
                float m10 = fmaf(a1.x, p1.x, a1.y);
                float m11 = fmaf(a1.z, p1.x, a1.w);
                // even k: m0*c + m1*s ; odd k: m1*c - m0*s
                float u0 = comp ? -p0.w : p0.z, w0 = comp ? p0.z : p0.w;
                float u1 = comp ? -p1.w : p1.z, w1 = comp ? p1.z : p1.w;
                acc0 = fmaf(m00, u0, acc0);
                b0   = fmaf(m01, w0, b0);
                acc1 = fmaf(m10, u1, acc1);
                b1   = fmaf(m11, w1, b1);
            }
            if (t < tmax) {
                float4 p0 = buf[beg + 2 * t + half];
                float4 a0 = tabM[(__float_as_int(p0.y) & 0xFFFF) + jj];
                float m00 = fmaf(a0.x, p0.x, a0.y);
                float m01 = fmaf(a0.z, p0.x, a0.w);
                float u0 = comp ? -p0.w : p0.z, w0 = comp ? p0.z : p0.w;
                acc0 = fmaf(m00, u0, acc0);
                b0   = fmaf(m01, w0, b0);
            }
            acc = (acc0 + b0) + (acc1 + b1);
        }
        acc += __shfl_xor(acc, 32, 64);
        if (half == 0) {
            float* dst = out + (mode ? (size_t)N * 32 : 0)
                       + (size_t)(lo + node) * 32 + k;
            *dst = acc;
        }
    }
}

extern "C" void kernel_launch(void* const* d_in, const int* in_sizes, int n_in,
                              void* d_out, int out_size, void* d_ws, size_t ws_size,
                              hipStream_t stream) {
    const float* v      = (const float*)d_in[0];
    const float* rot    = (const float*)d_in[1];
    const int*   ei     = (const int*)d_in[2];
    const float* msg_w1 = (const float*)d_in[3];
    const float* msg_b1 = (const float*)d_in[4];
    const float* msg_w2 = (const float*)d_in[5];
    const float* msg_b2 = (const float*)d_in[6];
    const float* sc_w1  = (const float*)d_in[7];
    const float* sc_b1  = (const float*)d_in[8];
    const float* sc_w2  = (const float*)d_in[9];
    const float* sc_b2  = (const float*)d_in[10];

    const int E = in_sizes[0] / 2;    // v is [E,2]
    const int N = out_size / 64;      // out = N*32 scalars + N*32 rot floats
    const int NBK = (N + NPB - 1) >> NPB_LOG;   // 1563 for N=100000

    float* ws  = (float*)d_ws;
    float* out = (float*)d_out;

    int*   gcur = (int*)(ws + WS_GCUR);
    uint2* pay  = (uint2*)(ws + WS_PAY);

    build_breakpoints<<<1, 256, 0, stream>>>(msg_w1, msg_b1, sc_w1, sc_b1, ws);
    build_tables<<<dim3(NROW, 2), NOUT, 0, stream>>>(
        msg_w1, msg_b1, msg_w2, msg_b2, sc_w1, sc_b1, sc_w2, sc_b2, ws);

    hipMemsetAsync(gcur, 0, (size_t)NBK * sizeof(int), stream);
    bucket_scatter<<<(E + EPB - 1) / EPB, SCT, 0, stream>>>(
        v, rot, ei + E, ws, gcur, pay, E, NBK);
    bucket_gather<<<NBK, 1024, 0, stream>>>(pay, gcur, ws, out, N);
}

// Round 14
// 109.216 us; speedup vs baseline: 1.4273x; 1.0025x over previous
//
#include <hip/hip_runtime.h>
#include <hip/hip_fp16.h>

#define H     96    // hidden width of both MLPs
#define NOUT  32    // outputs of both MLPs
#define NSEG  97    // H+1 piecewise-linear segments
#define SENTR 97    // all-zero sentinel table row
#define NROW  98
#define TPAD  128   // breakpoint array padded to pow2 for branchless search
#define TABQ  1568  // float4 per table (98*16)

#define NPB_LOG 6
#define NPB     64    // nodes per bucket
#define MAXBK   1600  // max buckets (N <= 102400)
#define EPB     4096  // edges per bucket_scatter block (391 blocks)
#define SCT     512   // scatter threads
#define EPT     8     // edges per thread in bucket_scatter (EPB/SCT)
#define CAP     1536  // fixed bucket region stride (mean 1024, +16 sigma)
#define BUFSZ   (CAP + NPB + 8)   // padded gather buffer capacity
#define NP      2     // payloads staged per thread in bucket_gather

// prescaled sentinel pk: hi16 = 97*32, lo16 = 97*16
#define SENT_PK ((3104 << 16) | 1552)

// ---- d_ws float-index layout -------------------------------------------
#define WS_TS_MSG   0          // float[128] sorted msg breakpoints (+inf pad)
#define WS_TS_SC    128        // float[128] sorted sc breakpoints
#define WS_ACS      256        // float2[98][32]  scalar (A, C+b2) [s][k], row 97 = 0
#define WS_ACM      6528       // float4[98][16]  msg (A0,C0,A1,C1) [s][j], row 97 = 0
#define WS_RANK     12800      // int[192]
#define WS_TSQ      13056      // float[256] merged breakpoints (+inf pad)
#define WS_CNTM     13312      // int[256]  cnt_m[q] = #msg-breakpoints < q-th
#define WS_GCUR     16384      // int[1600]  bucket cursors (counts after scatter)
#define WS_PAY      18048      // uint2[NBK*CAP + 1]  fixed-stride bucket payloads

// ---------------------------------------------------------------------------
// P1: breakpoints t_j = -b1_j/w1_j; per-MLP rank sort AND merged rank sort.
// ---------------------------------------------------------------------------
__global__ void build_breakpoints(const float* __restrict__ msg_w1,
                                  const float* __restrict__ msg_b1,
                                  const float* __restrict__ sc_w1,
                                  const float* __restrict__ sc_b1,
                                  float* __restrict__ ws) {
    __shared__ float t[2][H];
    __shared__ int is_msg[256];
    const int tid = threadIdx.x;        // 256 threads
    const int mlp = tid / H;
    const int j   = tid % H;
    is_msg[tid] = 0;
    if (tid < 2 * H) {
        const float* w1 = mlp ? sc_w1 : msg_w1;
        const float* b1 = mlp ? sc_b1 : msg_b1;
        float w = w1[j], b = b1[j];
        t[mlp][j] = (w == 0.0f) ? __builtin_inff() : (-b / w);
    }
    __syncthreads();
    if (tid < 2 * H) {
        float tj = t[mlp][j];
        int r = 0;
        for (int i = 0; i < H; ++i) {
            float ti = t[mlp][i];
            r += (ti < tj) || (ti == tj && i < j);
        }
        float* ts = ws + (mlp ? WS_TS_SC : WS_TS_MSG);
        ts[r] = tj;
        ((int*)(ws + WS_RANK))[mlp * H + j] = r;
        int cross = 0;
        if (mlp == 0) { for (int i = 0; i < H; ++i) cross += (t[1][i] <  tj); }
        else         { for (int i = 0; i < H; ++i) cross += (t[0][i] <= tj); }
        int q = r + cross;                 // 0..191, bijective
        ws[WS_TSQ + q] = tj;
        is_msg[q] = (mlp == 0);
    }
    if (tid < 2 * (TPAD - H)) {
        int m2 = tid / (TPAD - H);
        int p  = tid % (TPAD - H);
        ws[m2 * TPAD + H + p] = __builtin_inff();
    }
    if (tid < 64) ws[WS_TSQ + 192 + tid] = __builtin_inff();
    __syncthreads();
    if (tid == 0) {
        int acc = 0;
        int* cm = (int*)(ws + WS_CNTM);
        for (int i = 0; i < 256; ++i) { cm[i] = acc; acc += is_msg[i]; }
    }
}

// ---------------------------------------------------------------------------
// P2: per (segment, mlp): A,C with mlp(x) = A*x + C. Row 97 = zero sentinel.
// ---------------------------------------------------------------------------
__global__ void build_tables(const float* __restrict__ msg_w1,
                             const float* __restrict__ msg_b1,
                             const float* __restrict__ msg_w2,
                             const float* __restrict__ msg_b2,
                             const float* __restrict__ sc_w1,
                             const float* __restrict__ sc_b1,
                             const float* __restrict__ sc_w2,
                             const float* __restrict__ sc_b2,
                             float* __restrict__ ws) {
    const int s   = blockIdx.x;   // 0..97
    const int mlp = blockIdx.y;   // 0 = msg, 1 = sc
    const int k   = threadIdx.x;  // 0..31
    float A = 0.0f, C = 0.0f;
    if (s != SENTR) {
        const float* w1 = mlp ? sc_w1 : msg_w1;
        const float* b1 = mlp ? sc_b1 : msg_b1;
        const float* w2 = mlp ? sc_w2 : msg_w2;
        const float* b2 = mlp ? sc_b2 : msg_b2;
        const int* rank = (const int*)(ws + WS_RANK) + mlp * H;
        for (int j = 0; j < H; ++j) {
            float w = w1[j], b = b1[j];
            int   r = rank[j];
            bool active = (w > 0.0f) ? (r < s)
                        : (w < 0.0f) ? (r >= s)
                                     : (b > 0.0f);
            if (active) {
                float wk = w2[j * NOUT + k];
                A = fmaf(w, wk, A);
                C = fmaf(b, wk, C);
            }
        }
        C += b2[k];
    }
    if (mlp) {
        float* dst = ws + WS_ACS + 2 * (s * 32 + k);
        dst[0] = A; dst[1] = C;
    } else {
        float* dst = ws + WS_ACM + 4 * (s * 16 + (k >> 1)) + 2 * (k & 1);
        dst[0] = A; dst[1] = C;
    }
}

// ---------------------------------------------------------------------------
// K3: bucket scatter into fixed-stride regions (pay[b*CAP + i]).
// R14: ALL payload computation (v/rot loads, sqrt, merged search, f16 pack)
// moved into phase 1 — latency overlaps the scan phases; phase 4 is a pure
// LDS insert. Payload: w0 = f16(x)|f16(c)<<16 ; w1 = f16(s)|q<<16|(col&63)<<24
// ---------------------------------------------------------------------------
__global__ __launch_bounds__(SCT) void bucket_scatter(
    const float* __restrict__ v, const float* __restrict__ rot,
    const int* __restrict__ col, const float* __restrict__ ws,
    int* __restrict__ gcur, uint2* __restrict__ pay, int E, int NBK)
{
    __shared__ float ts_q[256];
    __shared__ int   lcnt[MAXBK];     // counts -> reused as insert cursor
    __shared__ int   lofs[MAXBK];     // local exclusive offsets
    __shared__ int   gdelta[MAXBK];   // b*CAP + global_base - local_offset
    __shared__ int   sh[SCT];
    __shared__ uint2 stage[EPB];      // 32 KB
    __shared__ int   gaddr[EPB];      // 16 KB

    const int tid = threadIdx.x;
    for (int i = tid; i < 256; i += SCT) ts_q[i] = ws[WS_TSQ + i];
    for (int i = tid; i < MAXBK; i += SCT) lcnt[i] = 0;
    __syncthreads();

    const int e0 = blockIdx.x * EPB;
    const int e1 = min(e0 + EPB, E);
    const int DUMP = NBK * CAP;       // spare slot for (unreachable) overflow

    // phase 1: load + compute payloads into registers + count
    int   col_r[EPT];
    uint2 pld[EPT];
    #pragma unroll
    for (int i = 0; i < EPT; ++i) {
        int e = e0 + i * SCT + tid;
        int c = (e < e1) ? col[e] : -1;
        col_r[i] = c;
        if (c >= 0) {
            float2 vv = *(const float2*)(v + 2 * (size_t)e);
            float4 r  = *(const float4*)(rot + 4 * (size_t)e);
            float  x  = sqrtf(vv.x * vv.x + vv.y * vv.y);
            int q = 0;
            #pragma unroll
            for (int st = 128; st > 0; st >>= 1)
                if (ts_q[q + st - 1] < x) q += st;
            unsigned hx = __half_as_ushort(__float2half(x));
            unsigned hc = __half_as_ushort(__float2half(r.x));
            unsigned hs = __half_as_ushort(__float2half(r.z));
            pld[i] = make_uint2(hx | (hc << 16),
                hs | ((unsigned)q << 16) | ((unsigned)(c & (NPB - 1)) << 24));
            atomicAdd(&lcnt[c >> NPB_LOG], 1);
        }
    }
    __syncthreads();

    // phase 2: local exclusive scan over MAXBK (4 buckets/thread + block scan)
    int b0 = tid * 4;
    int c0 = (b0 + 0 < MAXBK) ? lcnt[b0 + 0] : 0;
    int c1 = (b0 + 1 < MAXBK) ? lcnt[b0 + 1] : 0;
    int c2 = (b0 + 2 < MAXBK) ? lcnt[b0 + 2] : 0;
    int c3 = (b0 + 3 < MAXBK) ? lcnt[b0 + 3] : 0;
    int mysum = c0 + c1 + c2 + c3;
    sh[tid] = mysum;
    __syncthreads();
    for (int off = 1; off < SCT; off <<= 1) {
        int u = (tid >= off) ? sh[tid - off] : 0;
        __syncthreads();
        sh[tid] += u;
        __syncthreads();
    }
    {
        int run = sh[tid] - mysum;
        if (b0 + 0 < MAXBK) { lofs[b0 + 0] = run; run += c0; }
        if (b0 + 1 < MAXBK) { lofs[b0 + 1] = run; run += c1; }
        if (b0 + 2 < MAXBK) { lofs[b0 + 2] = run; run += c2; }
        if (b0 + 3 < MAXBK) { lofs[b0 + 3] = run; run += c3; }
    }
    __syncthreads();

    // phase 3: per-bucket global base from fixed-stride region
    for (int b = tid; b < NBK; b += SCT) {
        int c = lcnt[b];
        if (c) {
            int g = atomicAdd(&gcur[b], c);
            gdelta[b] = b * CAP + g - lofs[b];
        }
        lcnt[b] = lofs[b];            // reuse as insert cursor
    }
    __syncthreads();

    // phase 4: pure LDS insert (payloads already in registers)
    #pragma unroll
    for (int i = 0; i < EPT; ++i) {
        int c = col_r[i];
        if (c < 0) continue;
        int b    = c >> NPB_LOG;
        int lpos = atomicAdd(&lcnt[b], 1);
        int abspos = gdelta[b] + lpos;
        stage[lpos] = pld[i];
        gaddr[lpos] = (abspos - b * CAP < CAP) ? abspos : DUMP;
    }
    __syncthreads();

    // phase 5: streamed write-out (consecutive threads -> consecutive addrs)
    const int nB = e1 - e0;
    for (int i = tid; i < nB; i += SCT)
        pay[gaddr[i]] = stage[i];
}

// ---------------------------------------------------------------------------
// K4+gather fused (R13-proven, byte-identical): block = bucket (64 nodes),
// 1024 threads = 16 waves. Size from gcur[b], base = b*CAP.
// ---------------------------------------------------------------------------
__global__ __launch_bounds__(1024, 8) void bucket_gather(
    const uint2* __restrict__ pay, const int* __restrict__ gcur,
    const float* __restrict__ ws, float* __restrict__ out, int N)
{
    __shared__ float4 tabS[TABQ];        // scalar, viewed as float2[98*32]
    __shared__ float4 tabM[TABQ];        // msg table
    __shared__ float4 buf[BUFSZ];        // node-sorted padded payloads
    __shared__ int cntm[256];
    __shared__ int s_cnt[NPB], s_loff[NPB], s_cur[NPB];

    const int tid = threadIdx.x;
    const int b   = blockIdx.x;
    const int lo  = b << NPB_LOG;
    const int nn  = min(NPB, N - lo);
    const int bbeg = b * CAP;
    const int bsz  = min(gcur[b], CAP);

    {
        const float4* srcS = (const float4*)(ws + WS_ACS);
        const float4* srcM = (const float4*)(ws + WS_ACM);
        for (int i = tid; i < TABQ; i += 1024) { tabS[i] = srcS[i]; tabM[i] = srcM[i]; }
        if (tid < 256) cntm[tid] = ((const int*)(ws + WS_CNTM))[tid];
        if (tid < NPB) s_cnt[tid] = 0;
    }
    __syncthreads();

    // ---- Phase A: stage -> count -> wave0 scan (padded) -> insert+pad ----
    uint2 p[NP];
    int   loc[NP];
    #pragma unroll
    for (int i = 0; i < NP; ++i) {
        int idx = i * 1024 + tid;
        loc[i] = -1;
        if (idx < bsz) {
            p[i] = pay[bbeg + idx];
            loc[i] = (p[i].y >> 24) & (NPB - 1);
            atomicAdd(&s_cnt[loc[i]], 1);
        }
    }
    __syncthreads();
    if (tid < 64) {
        int cnt = s_cnt[tid];
        int pc  = (cnt + 1) & ~1;          // pair-padded size
        int incl = pc;
        #pragma unroll
        for (int off = 1; off < 64; off <<= 1) {
            int u = __shfl_up(incl, off, 64);
            if (tid >= off) incl += u;
        }
        s_loff[tid] = incl - pc;
        s_cur[tid]  = incl - pc;
    }
    __syncthreads();
    #pragma unroll
    for (int i = 0; i < NP; ++i) {
        if (loc[i] >= 0) {
            int pos = atomicAdd(&s_cur[loc[i]], 1);
            int q  = (p[i].y >> 16) & 255;
            int sm = cntm[q];
            int ss = q - sm;
            float x = __half2float(__ushort_as_half((unsigned short)(p[i].x & 0xFFFF)));
            float c = __half2float(__ushort_as_half((unsigned short)(p[i].x >> 16)));
            float s = __half2float(__ushort_as_half((unsigned short)(p[i].y & 0xFFFF)));
            buf[pos] = make_float4(x,
                __int_as_float(((ss << 5) << 16) | (sm << 4)), c, s);
        }
    }
    if (tid < NPB && (s_cnt[tid] & 1))
        buf[s_loff[tid] + s_cnt[tid]] =
            make_float4(0.f, __int_as_float(SENT_PK), 0.f, 0.f);
    __syncthreads();

    // ---- Phase B: 128 tasks (node x mode) over 16 waves, guard-free ----
    const int wv   = tid >> 6;
    const int lane = tid & 63;
    const int k    = lane & 31;
    const int half = lane >> 5;
    const float2* t2 = (const float2*)tabS;
    const int jj = k >> 1, comp = k & 1;

    for (int i = 0; i < 8; ++i) {
        int task = wv + (i << 4);     // 0..127
        int mode = task >> NPB_LOG;
        int node = task & (NPB - 1);
        if (node >= nn) continue;
        int beg  = s_loff[node];
        int tmax = (s_cnt[node] + 1) >> 1;   // complete pairs (padded)
        float acc = 0.f;
        if (mode == 0) {
            float a0c = 0.f, a1c = 0.f, acc0 = 0.f, acc1 = 0.f;
            int t = 0;
            for (; t + 2 <= tmax; t += 2) {
                float4 p0 = buf[beg + 2 * t + half];
                float4 p1 = buf[beg + 2 * t + 2 + half];
                float2 a0 = t2[((unsigned)__float_as_int(p0.y) >> 16) + k];
                float2 a1 = t2[((unsigned)__float_as_int(p1.y) >> 16) + k];
                acc0 = fmaf(a0.x, p0.x, acc0); a0c += a0.y;
                acc1 = fmaf(a1.x, p1.x, acc1); a1c += a1.y;
            }
            if (t < tmax) {
                float4 p0 = buf[beg + 2 * t + half];
                float2 a0 = t2[((unsigned)__float_as_int(p0.y) >> 16) + k];
                acc0 = fmaf(a0.x, p0.x, acc0); a0c += a0.y;
            }
            acc = (acc0 + a0c) + (acc1 + a1c);
        } else {
            float acc0 = 0.f, b0 = 0.f, acc1 = 0.f, b1 = 0.f;
            int t = 0;
            for (; t + 2 <= tmax; t += 2) {
                float4 p0 = buf[beg + 2 * t + half];
                float4 p1 = buf[beg + 2 * t + 2 + half];
                float4 a0 = tabM[(__float_as_int(p0.y) & 0xFFFF) + jj];
                float4 a1 = tabM[(__float_as_int(p1.y) & 0xFFFF) + jj];
                float m00 = fmaf(a0.x, p0.x, a0.y);
                float m01 = fmaf(a0.z, p0.x, a0.w);
                float m10 = fmaf(a1.x, p1.x, a1.y);
                float m11 = fmaf(a1.z, p1.x, a1.w);
                // even k: m0*c + m1*s ; odd k: m1*c - m0*s
                float u0 = comp ? -p0.w : p0.z, w0 = comp ? p0.z : p0.w;
                float u1 = comp ? -p1.w : p1.z, w1 = comp ? p1.z : p1.w;
                acc0 = fmaf(m00, u0, acc0);
                b0   = fmaf(m01, w0, b0);
                acc1 = fmaf(m10, u1, acc1);
                b1   = fmaf(m11, w1, b1);
            }
            if (t < tmax) {
                float4 p0 = buf[beg + 2 * t + half];
                float4 a0 = tabM[(__float_as_int(p0.y) & 0xFFFF) + jj];
                float m00 = fmaf(a0.x, p0.x, a0.y);
                float m01 = fmaf(a0.z, p0.x, a0.w);
                float u0 = comp ? -p0.w : p0.z, w0 = comp ? p0.z : p0.w;
                acc0 = fmaf(m00, u0, acc0);
                b0   = fmaf(m01, w0, b0);
            }
            acc = (acc0 + b0) + (acc1 + b1);
        }
        acc += __shfl_xor(acc, 32, 64);
        if (half == 0) {
            float* dst = out + (mode ? (size_t)N * 32 : 0)
                       + (size_t)(lo + node) * 32 + k;
            *dst = acc;
        }
    }
}

extern "C" void kernel_launch(void* const* d_in, const int* in_sizes, int n_in,
                              void* d_out, int out_size, void* d_ws, size_t ws_size,
                              hipStream_t stream) {
    const float* v      = (const float*)d_in[0];
    const float* rot    = (const float*)d_in[1];
    const int*   ei     = (const int*)d_in[2];
    const float* msg_w1 = (const float*)d_in[3];
    const float* msg_b1 = (const float*)d_in[4];
    const float* msg_w2 = (const float*)d_in[5];
    const float* msg_b2 = (const float*)d_in[6];
    const float* sc_w1  = (const float*)d_in[7];
    const float* sc_b1  = (const float*)d_in[8];
    const float* sc_w2  = (const float*)d_in[9];
    const float* sc_b2  = (const float*)d_in[10];

    const int E = in_sizes[0] / 2;    // v is [E,2]
    const int N = out_size / 64;      // out = N*32 scalars + N*32 rot floats
    const int NBK = (N + NPB - 1) >> NPB_LOG;   // 1563 for N=100000

    float* ws  = (float*)d_ws;
    float* out = (float*)d_out;

    int*   gcur = (int*)(ws + WS_GCUR);
    uint2* pay  = (uint2*)(ws + WS_PAY);

    build_breakpoints<<<1, 256, 0, stream>>>(msg_w1, msg_b1, sc_w1, sc_b1, ws);
    build_tables<<<dim3(NROW, 2), NOUT, 0, stream>>>(
        msg_w1, msg_b1, msg_w2, msg_b2, sc_w1, sc_b1, sc_w2, sc_b2, ws);

    hipMemsetAsync(gcur, 0, (size_t)NBK * sizeof(int), stream);
    bucket_scatter<<<(E + EPB - 1) / EPB, SCT, 0, stream>>>(
        v, rot, ei + E, ws, gcur, pay, E, NBK);
    bucket_gather<<<NBK, 1024, 0, stream>>>(pay, gcur, ws, out, N);
}

// Round 15
// 97.339 us; speedup vs baseline: 1.6014x; 1.1220x over previous
//
#include <hip/hip_runtime.h>
#include <hip/hip_fp16.h>

#define H     96    // hidden width of both MLPs
#define NOUT  32    // outputs of both MLPs
#define NSEG  97    // H+1 piecewise-linear segments
#define SENTR 97    // all-zero sentinel table row
#define NROW  98
#define TABQ  1568  // float4 per table (98*16)

#define NPB_LOG 6
#define NPB     64    // nodes per bucket
#define MAXBK   1600  // max buckets (N <= 102400)
#define SGRID   512   // scatter grid (exactly 2 blocks/CU)
#define SCT     512   // scatter threads
#define EPTS    7     // max edges per thread (ceil(ceil(E/512)/512)), E<=1.83M
#define ESTG    (EPTS * SCT)  // 3584 LDS staging slots
#define CAP     1536  // fixed bucket region stride (mean 1024, +16 sigma)
#define BUFSZ   (CAP + NPB + 8)   // padded gather buffer capacity
#define NP      2     // payloads staged per thread in bucket_gather

// prescaled sentinel pk: hi16 = 97*32, lo16 = 97*16
#define SENT_PK ((3104 << 16) | 1552)

// ---- d_ws float-index layout -------------------------------------------
#define WS_ACS      256        // float2[98][32]  scalar (A, C+b2) [s][k], row 97 = 0
#define WS_ACM      6528       // float4[98][16]  msg (A0,C0,A1,C1) [s][j], row 97 = 0
#define WS_TSQ      13056      // float[256] merged breakpoints (+inf pad)
#define WS_CNTM     13312      // int[256]  cnt_m[q] = #msg-breakpoints < q-th
#define WS_GCUR     16384      // int[1600]  bucket cursors (counts after scatter)
#define WS_PAY      18048      // uint2[NBK*CAP + 1]  fixed-stride bucket payloads

// ---------------------------------------------------------------------------
// P12: FUSED breakpoints + tables. Grid (98, 2), 96 threads/block.
// Each block recomputes its MLP's breakpoints + ranks locally (cheap).
// Block (97,0): also writes merged ts_q + cntm. Block (97,1): zeroes gcur.
// Table A,C sum split over 3 thread-groups (32 j's each) + LDS reduce.
// ---------------------------------------------------------------------------
__global__ __launch_bounds__(96) void build_tables(
    const float* __restrict__ msg_w1, const float* __restrict__ msg_b1,
    const float* __restrict__ msg_w2, const float* __restrict__ msg_b2,
    const float* __restrict__ sc_w1,  const float* __restrict__ sc_b1,
    const float* __restrict__ sc_w2,  const float* __restrict__ sc_b2,
    float* __restrict__ ws, int* __restrict__ gcur, int NBK)
{
    const int s    = blockIdx.x;   // 0..97
    const int mlp  = blockIdx.y;   // 0 = msg, 1 = sc
    const int tid  = threadIdx.x;  // 0..95
    const int part = tid >> 5;     // 0..2
    const int k    = tid & 31;

    __shared__ float tm[H], to[H];        // own / other breakpoints
    __shared__ int   rnk[H];
    __shared__ float pA[3][32], pC[3][32];
    __shared__ unsigned char ismsg[256];

    const float* w1  = mlp ? sc_w1 : msg_w1;
    const float* b1  = mlp ? sc_b1 : msg_b1;
    const float* w2  = mlp ? sc_w2 : msg_w2;
    const float* b2  = mlp ? sc_b2 : msg_b2;
    const float* w1o = mlp ? msg_w1 : sc_w1;
    const float* b1o = mlp ? msg_b1 : sc_b1;

    {
        float w  = w1[tid],  b  = b1[tid];
        float wo = w1o[tid], bo = b1o[tid];
        tm[tid] = (w  == 0.f) ? __builtin_inff() : (-b  / w);
        to[tid] = (wo == 0.f) ? __builtin_inff() : (-bo / wo);
    }
    __syncthreads();
    {
        float tj = tm[tid];
        int r = 0;
        for (int i = 0; i < H; ++i) {
            float ti = tm[i];
            r += (ti < tj) || (ti == tj && i < tid);
        }
        rnk[tid] = r;
    }
    __syncthreads();

    // ---- table row (partial sums over 3 j-groups) ----
    float A = 0.f, C = 0.f;
    if (s != SENTR) {
        const int j0 = part * 32;
        for (int j = j0; j < j0 + 32; ++j) {
            float w = w1[j], b = b1[j];
            int   r = rnk[j];
            bool active = (w > 0.f) ? (r < s)
                        : (w < 0.f) ? (r >= s)
                                    : (b > 0.f);
            if (active) {
                float wk = w2[j * NOUT + k];
                A = fmaf(w, wk, A);
                C = fmaf(b, wk, C);
            }
        }
    }
    pA[part][k] = A; pC[part][k] = C;
    __syncthreads();
    if (part == 0) {
        float Af = pA[0][k] + pA[1][k] + pA[2][k];
        float Cf = pC[0][k] + pC[1][k] + pC[2][k] + b2[k];
        if (s == SENTR) { Af = 0.f; Cf = 0.f; }
        if (mlp) {
            float* dst = ws + WS_ACS + 2 * (s * 32 + k);
            dst[0] = Af; dst[1] = Cf;
        } else {
            float* dst = ws + WS_ACM + 4 * (s * 16 + (k >> 1)) + 2 * (k & 1);
            dst[0] = Af; dst[1] = Cf;
        }
    }

    // ---- side duties (block-uniform branches) ----
    if (s == SENTR) {
        if (mlp == 1) {
            for (int i = tid; i < NBK; i += 96) gcur[i] = 0;
        } else {
            // merged breakpoint array: tm = msg, to = sc
            for (int i = tid; i < 256; i += 96) ismsg[i] = 0;
            __syncthreads();
            {   // msg element tid: merged rank (msg precedes sc on ties)
                float tj = tm[tid];
                int cross = 0;
                for (int i = 0; i < H; ++i) cross += (to[i] < tj);
                int q = rnk[tid] + cross;          // 0..191 bijective
                ws[WS_TSQ + q] = tj;
                ismsg[q] = 1;
            }
            {   // sc element tid
                float tj = to[tid];
                int r = 0;
                for (int i = 0; i < H; ++i) {
                    float ti = to[i];
                    r += (ti < tj) || (ti == tj && i < tid);
                }
                int cross = 0;
                for (int i = 0; i < H; ++i) cross += (tm[i] <= tj);
                ws[WS_TSQ + (r + cross)] = tj;
            }
            for (int i = 192 + tid; i < 256; i += 96)
                ws[WS_TSQ + i] = __builtin_inff();
            __syncthreads();
            if (tid == 0) {
                int acc = 0;
                int* cm = (int*)(ws + WS_CNTM);
                for (int i = 0; i < 256; ++i) { cm[i] = acc; acc += ismsg[i]; }
            }
        }
    }
}

// ---------------------------------------------------------------------------
// K3: bucket scatter into fixed-stride regions (pay[b*CAP + i]).
// Grid = 512 blocks (exactly 2/CU, balanced). Payloads computed in phase 1
// (latency overlaps scan). LDS-sorted coalesced writes, 8B payloads.
// payload: w0 = f16(x)|f16(c)<<16 ; w1 = f16(s)|q<<16|(col&63)<<24
// ---------------------------------------------------------------------------
__global__ __launch_bounds__(SCT) void bucket_scatter(
    const float* __restrict__ v, const float* __restrict__ rot,
    const int* __restrict__ col, const float* __restrict__ ws,
    int* __restrict__ gcur, uint2* __restrict__ pay, int E, int NBK, int epb)
{
    __shared__ float ts_q[256];
    __shared__ int   lcnt[MAXBK];     // counts -> reused as insert cursor
    __shared__ int   lofs[MAXBK];     // local exclusive offsets
    __shared__ int   gdelta[MAXBK];   // b*CAP + global_base - local_offset
    __shared__ int   sh[SCT];
    __shared__ uint2 stage[ESTG];     // 28 KB
    __shared__ int   gaddr[ESTG];     // 14 KB

    const int tid = threadIdx.x;
    for (int i = tid; i < 256; i += SCT) ts_q[i] = ws[WS_TSQ + i];
    for (int i = tid; i < MAXBK; i += SCT) lcnt[i] = 0;
    __syncthreads();

    const int e0 = blockIdx.x * epb;
    const int e1 = min(e0 + epb, E);
    const int DUMP = NBK * CAP;       // spare slot for (unreachable) overflow

    // phase 1: load + compute payloads into registers + count
    int   col_r[EPTS];
    uint2 pld[EPTS];
    #pragma unroll
    for (int i = 0; i < EPTS; ++i) {
        int e = e0 + i * SCT + tid;
        int c = (e < e1) ? col[e] : -1;
        col_r[i] = c;
        if (c >= 0) {
            float2 vv = *(const float2*)(v + 2 * (size_t)e);
            float4 r  = *(const float4*)(rot + 4 * (size_t)e);
            float  x  = sqrtf(vv.x * vv.x + vv.y * vv.y);
            int q = 0;
            #pragma unroll
            for (int st = 128; st > 0; st >>= 1)
                if (ts_q[q + st - 1] < x) q += st;
            unsigned hx = __half_as_ushort(__float2half(x));
            unsigned hc = __half_as_ushort(__float2half(r.x));
            unsigned hs = __half_as_ushort(__float2half(r.z));
            pld[i] = make_uint2(hx | (hc << 16),
                hs | ((unsigned)q << 16) | ((unsigned)(c & (NPB - 1)) << 24));
            atomicAdd(&lcnt[c >> NPB_LOG], 1);
        }
    }
    __syncthreads();

    // phase 2: local exclusive scan over MAXBK (4 buckets/thread + block scan)
    int b0 = tid * 4;
    int c0 = (b0 + 0 < MAXBK) ? lcnt[b0 + 0] : 0;
    int c1 = (b0 + 1 < MAXBK) ? lcnt[b0 + 1] : 0;
    int c2 = (b0 + 2 < MAXBK) ? lcnt[b0 + 2] : 0;
    int c3 = (b0 + 3 < MAXBK) ? lcnt[b0 + 3] : 0;
    int mysum = c0 + c1 + c2 + c3;
    sh[tid] = mysum;
    __syncthreads();
    for (int off = 1; off < SCT; off <<= 1) {
        int u = (tid >= off) ? sh[tid - off] : 0;
        __syncthreads();
        sh[tid] += u;
        __syncthreads();
    }
    {
        int run = sh[tid] - mysum;
        if (b0 + 0 < MAXBK) { lofs[b0 + 0] = run; run += c0; }
        if (b0 + 1 < MAXBK) { lofs[b0 + 1] = run; run += c1; }
        if (b0 + 2 < MAXBK) { lofs[b0 + 2] = run; run += c2; }
        if (b0 + 3 < MAXBK) { lofs[b0 + 3] = run; run += c3; }
    }
    __syncthreads();

    // phase 3: per-bucket global base from fixed-stride region
    for (int b = tid; b < NBK; b += SCT) {
        int c = lcnt[b];
        if (c) {
            int g = atomicAdd(&gcur[b], c);
            gdelta[b] = b * CAP + g - lofs[b];
        }
        lcnt[b] = lofs[b];            // reuse as insert cursor
    }
    __syncthreads();

    // phase 4: pure LDS insert (payloads already in registers)
    #pragma unroll
    for (int i = 0; i < EPTS; ++i) {
        int c = col_r[i];
        if (c < 0) continue;
        int b    = c >> NPB_LOG;
        int lpos = atomicAdd(&lcnt[b], 1);
        int abspos = gdelta[b] + lpos;
        stage[lpos] = pld[i];
        gaddr[lpos] = (abspos - b * CAP < CAP) ? abspos : DUMP;
    }
    __syncthreads();

    // phase 5: streamed write-out (consecutive threads -> consecutive addrs)
    const int nB = e1 - e0;
    for (int i = tid; i < nB; i += SCT)
        pay[gaddr[i]] = stage[i];
}

// ---------------------------------------------------------------------------
// K4+gather fused (R13-proven, byte-identical): block = bucket (64 nodes),
// 1024 threads = 16 waves. Size from gcur[b], base = b*CAP.
// ---------------------------------------------------------------------------
__global__ __launch_bounds__(1024, 8) void bucket_gather(
    const uint2* __restrict__ pay, const int* __restrict__ gcur,
    const float* __restrict__ ws, float* __restrict__ out, int N)
{
    __shared__ float4 tabS[TABQ];        // scalar, viewed as float2[98*32]
    __shared__ float4 tabM[TABQ];        // msg table
    __shared__ float4 buf[BUFSZ];        // node-sorted padded payloads
    __shared__ int cntm[256];
    __shared__ int s_cnt[NPB], s_loff[NPB], s_cur[NPB];

    const int tid = threadIdx.x;
    const int b   = blockIdx.x;
    const int lo  = b << NPB_LOG;
    const int nn  = min(NPB, N - lo);
    const int bbeg = b * CAP;
    const int bsz  = min(gcur[b], CAP);

    {
        const float4* srcS = (const float4*)(ws + WS_ACS);
        const float4* srcM = (const float4*)(ws + WS_ACM);
        for (int i = tid; i < TABQ; i += 1024) { tabS[i] = srcS[i]; tabM[i] = srcM[i]; }
        if (tid < 256) cntm[tid] = ((const int*)(ws + WS_CNTM))[tid];
        if (tid < NPB) s_cnt[tid] = 0;
    }
    __syncthreads();

    // ---- Phase A: stage -> count -> wave0 scan (padded) -> insert+pad ----
    uint2 p[NP];
    int   loc[NP];
    #pragma unroll
    for (int i = 0; i < NP; ++i) {
        int idx = i * 1024 + tid;
        loc[i] = -1;
        if (idx < bsz) {
            p[i] = pay[bbeg + idx];
            loc[i] = (p[i].y >> 24) & (NPB - 1);
            atomicAdd(&s_cnt[loc[i]], 1);
        }
    }
    __syncthreads();
    if (tid < 64) {
        int cnt = s_cnt[tid];
        int pc  = (cnt + 1) & ~1;          // pair-padded size
        int incl = pc;
        #pragma unroll
        for (int off = 1; off < 64; off <<= 1) {
            int u = __shfl_up(incl, off, 64);
            if (tid >= off) incl += u;
        }
        s_loff[tid] = incl - pc;
        s_cur[tid]  = incl - pc;
    }
    __syncthreads();
    #pragma unroll
    for (int i = 0; i < NP; ++i) {
        if (loc[i] >= 0) {
            int pos = atomicAdd(&s_cur[loc[i]], 1);
            int q  = (p[i].y >> 16) & 255;
            int sm = cntm[q];
            int ss = q - sm;
            float x = __half2float(__ushort_as_half((unsigned short)(p[i].x & 0xFFFF)));
            float c = __half2float(__ushort_as_half((unsigned short)(p[i].x >> 16)));
            float s = __half2float(__ushort_as_half((unsigned short)(p[i].y & 0xFFFF)));
            buf[pos] = make_float4(x,
                __int_as_float(((ss << 5) << 16) | (sm << 4)), c, s);
        }
    }
    if (tid < NPB && (s_cnt[tid] & 1))
        buf[s_loff[tid] + s_cnt[tid]] =
            make_float4(0.f, __int_as_float(SENT_PK), 0.f, 0.f);
    __syncthreads();

    // ---- Phase B: 128 tasks (node x mode) over 16 waves, guard-free ----
    const int wv   = tid >> 6;
    const int lane = tid & 63;
    const int k    = lane & 31;
    const int half = lane >> 5;
    const float2* t2 = (const float2*)tabS;
    const int jj = k >> 1, comp = k & 1;

    for (int i = 0; i < 8; ++i) {
        int task = wv + (i << 4);     // 0..127
        int mode = task >> NPB_LOG;
        int node = task & (NPB - 1);
        if (node >= nn) continue;
        int beg  = s_loff[node];
        int tmax = (s_cnt[node] + 1) >> 1;   // complete pairs (padded)
        float acc = 0.f;
        if (mode == 0) {
            float a0c = 0.f, a1c = 0.f, acc0 = 0.f, acc1 = 0.f;
            int t = 0;
            for (; t + 2 <= tmax; t += 2) {
                float4 p0 = buf[beg + 2 * t + half];
                float4 p1 = buf[beg + 2 * t + 2 + half];
                float2 a0 = t2[((unsigned)__float_as_int(p0.y) >> 16) + k];
                float2 a1 = t2[((unsigned)__float_as_int(p1.y) >> 16) + k];
                acc0 = fmaf(a0.x, p0.x, acc0); a0c += a0.y;
                acc1 = fmaf(a1.x, p1.x, acc1); a1c += a1.y;
            }
            if (t < tmax) {
                float4 p0 = buf[beg + 2 * t + half];
                float2 a0 = t2[((unsigned)__float_as_int(p0.y) >> 16) + k];
                acc0 = fmaf(a0.x, p0.x, acc0); a0c += a0.y;
            }
            acc = (acc0 + a0c) + (acc1 + a1c);
        } else {
            float acc0 = 0.f, b0 = 0.f, acc1 = 0.f, b1 = 0.f;
            int t = 0;
            for (; t + 2 <= tmax; t += 2) {
                float4 p0 = buf[beg + 2 * t + half];
                float4 p1 = buf[beg + 2 * t + 2 + half];
                float4 a0 = tabM[(__float_as_int(p0.y) & 0xFFFF) + jj];
                float4 a1 = tabM[(__float_as_int(p1.y) & 0xFFFF) + jj];
                float m00 = fmaf(a0.x, p0.x, a0.y);
                float m01 = fmaf(a0.z, p0.x, a0.w);
                float m10 = fmaf(a1.x, p1.x, a1.y);
                float m11 = fmaf(a1.z, p1.x, a1.w);
                // even k: m0*c + m1*s ; odd k: m1*c - m0*s
                float u0 = comp ? -p0.w : p0.z, w0 = comp ? p0.z : p0.w;
                float u1 = comp ? -p1.w : p1.z, w1 = comp ? p1.z : p1.w;
                acc0 = fmaf(m00, u0, acc0);
                b0   = fmaf(m01, w0, b0);
                acc1 = fmaf(m10, u1, acc1);
                b1   = fmaf(m11, w1, b1);
            }
            if (t < tmax) {
                float4 p0 = buf[beg + 2 * t + half];
                float4 a0 = tabM[(__float_as_int(p0.y) & 0xFFFF) + jj];
                float m00 = fmaf(a0.x, p0.x, a0.y);
                float m01 = fmaf(a0.z, p0.x, a0.w);
                float u0 = comp ? -p0.w : p0.z, w0 = comp ? p0.z : p0.w;
                acc0 = fmaf(m00, u0, acc0);
                b0   = fmaf(m01, w0, b0);
            }
            acc = (acc0 + b0) + (acc1 + b1);
        }
        acc += __shfl_xor(acc, 32, 64);
        if (half == 0) {
            float* dst = out + (mode ? (size_t)N * 32 : 0)
                       + (size_t)(lo + node) * 32 + k;
            *dst = acc;
        }
    }
}

extern "C" void kernel_launch(void* const* d_in, const int* in_sizes, int n_in,
                              void* d_out, int out_size, void* d_ws, size_t ws_size,
                              hipStream_t stream) {
    const float* v      = (const float*)d_in[0];
    const float* rot    = (const float*)d_in[1];
    const int*   ei     = (const int*)d_in[2];
    const float* msg_w1 = (const float*)d_in[3];
    const float* msg_b1 = (const float*)d_in[4];
    const float* msg_w2 = (const float*)d_in[5];
    const float* msg_b2 = (const float*)d_in[6];
    const float* sc_w1  = (const float*)d_in[7];
    const float* sc_b1  = (const float*)d_in[8];
    const float* sc_w2  = (const float*)d_in[9];
    const float* sc_b2  = (const float*)d_in[10];

    const int E = in_sizes[0] / 2;    // v is [E,2]
    const int N = out_size / 64;      // out = N*32 scalars + N*32 rot floats
    const int NBK = (N + NPB - 1) >> NPB_LOG;   // 1563 for N=100000

    float* ws  = (float*)d_ws;
    float* out = (float*)d_out;

    int*   gcur = (int*)(ws + WS_GCUR);
    uint2* pay  = (uint2*)(ws + WS_PAY);

    const int epb = (E + SGRID - 1) / SGRID;    // 3125 for E=1.6M (<= ESTG)

    build_tables<<<dim3(NROW, 2), 96, 0, stream>>>(
        msg_w1, msg_b1, msg_w2, msg_b2, sc_w1, sc_b1, sc_w2, sc_b2,
        ws, gcur, NBK);
    bucket_scatter<<<SGRID, SCT, 0, stream>>>(
        v, rot, ei + E, ws, gcur, pay, E, NBK, epb);
    bucket_gather<<<NBK, 1024, 0, stream>>>(pay, gcur, ws, out, N);
}

// Round 16
// 89.515 us; speedup vs baseline: 1.7414x; 1.0874x over previous
//
#include <hip/hip_runtime.h>
#include <hip/hip_fp16.h>

#define H     96    // hidden width of both MLPs
#define NOUT  32    // outputs of both MLPs
#define NSEG  97    // H+1 piecewise-linear segments
#define SENTR 97    // all-zero sentinel table row
#define NROW  98
#define TABQ  1568  // float4 per table (98*16)

#define NPB_LOG 6
#define NPB     64    // nodes per bucket
#define MAXBK   1600  // max buckets (N <= 102400)
#define SGRID   512   // scatter grid (exactly 2 blocks/CU)
#define SCT     512   // scatter threads
#define EPTS    7     // max edges per thread (ceil(ceil(E/512)/512)), E<=1.83M
#define ESTG    (EPTS * SCT)  // 3584 LDS staging slots
#define CAP     1536  // fixed bucket region stride (mean 1024, +16 sigma)
#define BUFSZ   (CAP + NPB + 8)   // padded gather buffer capacity
#define NP      2     // payloads staged per thread in bucket_gather

// prescaled sentinel pk: hi16 = 97*32 (t2 row 97), lo16 = 97*16 (tabM row 97)
#define SENT_PK ((3104 << 16) | 1552)

// ---- d_ws float-index layout -------------------------------------------
#define WS_ACS      256        // float2[98][32]  scalar (A, C+b2) [s][k], row 97 = 0
#define WS_ACM      6528       // float4[98][16]  msg (A0,C0,A1,C1) [s][j], row 97 = 0
#define WS_TSQ      13056      // float[256] merged breakpoints (+inf pad)
#define WS_CNTM     13312      // int[256]  cnt_m[q] = #msg-breakpoints < q-th
#define WS_GCUR     16384      // int[1600]  bucket cursors (counts after scatter)
#define WS_PAY      18048      // uint2[NBK*CAP + 1]  fixed-stride bucket payloads

// ---------------------------------------------------------------------------
// P12: FUSED breakpoints + tables (R15-proven). Grid (98, 2), 96 thr/block.
// Block (97,0) also writes merged ts_q + cntm; block (97,1) zeroes gcur.
// ---------------------------------------------------------------------------
__global__ __launch_bounds__(96) void build_tables(
    const float* __restrict__ msg_w1, const float* __restrict__ msg_b1,
    const float* __restrict__ msg_w2, const float* __restrict__ msg_b2,
    const float* __restrict__ sc_w1,  const float* __restrict__ sc_b1,
    const float* __restrict__ sc_w2,  const float* __restrict__ sc_b2,
    float* __restrict__ ws, int* __restrict__ gcur, int NBK)
{
    const int s    = blockIdx.x;   // 0..97
    const int mlp  = blockIdx.y;   // 0 = msg, 1 = sc
    const int tid  = threadIdx.x;  // 0..95
    const int part = tid >> 5;     // 0..2
    const int k    = tid & 31;

    __shared__ float tm[H], to[H];        // own / other breakpoints
    __shared__ int   rnk[H];
    __shared__ float pA[3][32], pC[3][32];
    __shared__ unsigned char ismsg[256];

    const float* w1  = mlp ? sc_w1 : msg_w1;
    const float* b1  = mlp ? sc_b1 : msg_b1;
    const float* w2  = mlp ? sc_w2 : msg_w2;
    const float* b2  = mlp ? sc_b2 : msg_b2;
    const float* w1o = mlp ? msg_w1 : sc_w1;
    const float* b1o = mlp ? msg_b1 : sc_b1;

    {
        float w  = w1[tid],  b  = b1[tid];
        float wo = w1o[tid], bo = b1o[tid];
        tm[tid] = (w  == 0.f) ? __builtin_inff() : (-b  / w);
        to[tid] = (wo == 0.f) ? __builtin_inff() : (-bo / wo);
    }
    __syncthreads();
    {
        float tj = tm[tid];
        int r = 0;
        for (int i = 0; i < H; ++i) {
            float ti = tm[i];
            r += (ti < tj) || (ti == tj && i < tid);
        }
        rnk[tid] = r;
    }
    __syncthreads();

    float A = 0.f, C = 0.f;
    if (s != SENTR) {
        const int j0 = part * 32;
        for (int j = j0; j < j0 + 32; ++j) {
            float w = w1[j], b = b1[j];
            int   r = rnk[j];
            bool active = (w > 0.f) ? (r < s)
                        : (w < 0.f) ? (r >= s)
                                    : (b > 0.f);
            if (active) {
                float wk = w2[j * NOUT + k];
                A = fmaf(w, wk, A);
                C = fmaf(b, wk, C);
            }
        }
    }
    pA[part][k] = A; pC[part][k] = C;
    __syncthreads();
    if (part == 0) {
        float Af = pA[0][k] + pA[1][k] + pA[2][k];
        float Cf = pC[0][k] + pC[1][k] + pC[2][k] + b2[k];
        if (s == SENTR) { Af = 0.f; Cf = 0.f; }
        if (mlp) {
            float* dst = ws + WS_ACS + 2 * (s * 32 + k);
            dst[0] = Af; dst[1] = Cf;
        } else {
            float* dst = ws + WS_ACM + 4 * (s * 16 + (k >> 1)) + 2 * (k & 1);
            dst[0] = Af; dst[1] = Cf;
        }
    }

    if (s == SENTR) {
        if (mlp == 1) {
            for (int i = tid; i < NBK; i += 96) gcur[i] = 0;
        } else {
            for (int i = tid; i < 256; i += 96) ismsg[i] = 0;
            __syncthreads();
            {   // msg element tid: merged rank (msg precedes sc on ties)
                float tj = tm[tid];
                int cross = 0;
                for (int i = 0; i < H; ++i) cross += (to[i] < tj);
                int q = rnk[tid] + cross;          // 0..191 bijective
                ws[WS_TSQ + q] = tj;
                ismsg[q] = 1;
            }
            {   // sc element tid
                float tj = to[tid];
                int r = 0;
                for (int i = 0; i < H; ++i) {
                    float ti = to[i];
                    r += (ti < tj) || (ti == tj && i < tid);
                }
                int cross = 0;
                for (int i = 0; i < H; ++i) cross += (tm[i] <= tj);
                ws[WS_TSQ + (r + cross)] = tj;
            }
            for (int i = 192 + tid; i < 256; i += 96)
                ws[WS_TSQ + i] = __builtin_inff();
            __syncthreads();
            if (tid == 0) {
                int acc = 0;
                int* cm = (int*)(ws + WS_CNTM);
                for (int i = 0; i < 256; ++i) { cm[i] = acc; acc += ismsg[i]; }
            }
        }
    }
}

// ---------------------------------------------------------------------------
// K3: bucket scatter into fixed-stride regions (pay[b*CAP + i]).
// R16: phase-2 scan via wave shfl (2 barriers instead of 18).
// payload: w0 = f16(x)|f16(c)<<16 ; w1 = f16(s)|q<<16|(col&63)<<24
// ---------------------------------------------------------------------------
__global__ __launch_bounds__(SCT) void bucket_scatter(
    const float* __restrict__ v, const float* __restrict__ rot,
    const int* __restrict__ col, const float* __restrict__ ws,
    int* __restrict__ gcur, uint2* __restrict__ pay, int E, int NBK, int epb)
{
    __shared__ float ts_q[256];
    __shared__ int   lcnt[MAXBK];     // counts -> reused as insert cursor
    __shared__ int   lofs[MAXBK];     // local exclusive offsets
    __shared__ int   gdelta[MAXBK];   // b*CAP + global_base - local_offset
    __shared__ int   wsum[8], woff[8];
    __shared__ uint2 stage[ESTG];     // 28 KB
    __shared__ int   gaddr[ESTG];     // 14 KB

    const int tid  = threadIdx.x;
    const int lane = tid & 63;
    const int wv   = tid >> 6;
    for (int i = tid; i < 256; i += SCT) ts_q[i] = ws[WS_TSQ + i];
    for (int i = tid; i < MAXBK; i += SCT) lcnt[i] = 0;
    __syncthreads();

    const int e0 = blockIdx.x * epb;
    const int e1 = min(e0 + epb, E);
    const int DUMP = NBK * CAP;       // spare slot for (unreachable) overflow

    // phase 1: load + compute payloads into registers + count
    int   col_r[EPTS];
    uint2 pld[EPTS];
    #pragma unroll
    for (int i = 0; i < EPTS; ++i) {
        int e = e0 + i * SCT + tid;
        int c = (e < e1) ? col[e] : -1;
        col_r[i] = c;
        if (c >= 0) {
            float2 vv = *(const float2*)(v + 2 * (size_t)e);
            float4 r  = *(const float4*)(rot + 4 * (size_t)e);
            float  x  = sqrtf(vv.x * vv.x + vv.y * vv.y);
            int q = 0;
            #pragma unroll
            for (int st = 128; st > 0; st >>= 1)
                if (ts_q[q + st - 1] < x) q += st;
            unsigned hx = __half_as_ushort(__float2half(x));
            unsigned hc = __half_as_ushort(__float2half(r.x));
            unsigned hs = __half_as_ushort(__float2half(r.z));
            pld[i] = make_uint2(hx | (hc << 16),
                hs | ((unsigned)q << 16) | ((unsigned)(c & (NPB - 1)) << 24));
            atomicAdd(&lcnt[c >> NPB_LOG], 1);
        }
    }
    __syncthreads();

    // phase 2: exclusive scan over MAXBK via wave-shfl (2 barriers total)
    int b0 = tid * 4;
    int c0 = (b0 + 0 < MAXBK) ? lcnt[b0 + 0] : 0;
    int c1 = (b0 + 1 < MAXBK) ? lcnt[b0 + 1] : 0;
    int c2 = (b0 + 2 < MAXBK) ? lcnt[b0 + 2] : 0;
    int c3 = (b0 + 3 < MAXBK) ? lcnt[b0 + 3] : 0;
    int mysum = c0 + c1 + c2 + c3;
    int incl  = mysum;
    #pragma unroll
    for (int off = 1; off < 64; off <<= 1) {
        int u = __shfl_up(incl, off, 64);
        if (lane >= off) incl += u;
    }
    if (lane == 63) wsum[wv] = incl;
    __syncthreads();
    if (wv == 0 && lane < 8) {
        int vv2 = wsum[lane];
        int s2  = vv2;
        #pragma unroll
        for (int off = 1; off < 8; off <<= 1) {
            int u = __shfl_up(s2, off, 8);
            if (lane >= off) s2 += u;
        }
        woff[lane] = s2 - vv2;   // exclusive across waves
    }
    __syncthreads();
    {
        int run = (incl - mysum) + woff[wv];
        if (b0 + 0 < MAXBK) { lofs[b0 + 0] = run; run += c0; }
        if (b0 + 1 < MAXBK) { lofs[b0 + 1] = run; run += c1; }
        if (b0 + 2 < MAXBK) { lofs[b0 + 2] = run; run += c2; }
        if (b0 + 3 < MAXBK) { lofs[b0 + 3] = run; run += c3; }
    }
    __syncthreads();

    // phase 3: per-bucket global base from fixed-stride region
    for (int b = tid; b < NBK; b += SCT) {
        int c = lcnt[b];
        if (c) {
            int g = atomicAdd(&gcur[b], c);
            gdelta[b] = b * CAP + g - lofs[b];
        }
        lcnt[b] = lofs[b];            // reuse as insert cursor
    }
    __syncthreads();

    // phase 4: pure LDS insert (payloads already in registers)
    #pragma unroll
    for (int i = 0; i < EPTS; ++i) {
        int c = col_r[i];
        if (c < 0) continue;
        int b    = c >> NPB_LOG;
        int lpos = atomicAdd(&lcnt[b], 1);
        int abspos = gdelta[b] + lpos;
        stage[lpos] = pld[i];
        gaddr[lpos] = (abspos - b * CAP < CAP) ? abspos : DUMP;
    }
    __syncthreads();

    // phase 5: streamed write-out (consecutive threads -> consecutive addrs)
    const int nB = e1 - e0;
    for (int i = tid; i < nB; i += SCT)
        pay[gaddr[i]] = stage[i];
}

// ---------------------------------------------------------------------------
// K4+gather fused: block = bucket (64 nodes), 1024 threads = 16 waves.
// R16: FUSED MODES — one task = one node, computing scalar AND rot outputs
// in a single pass (payload read/pk-extract once; task setup amortized 2x).
// Phase A unchanged from R13. 64 tasks over 16 waves (4 iterations).
// ---------------------------------------------------------------------------
__global__ __launch_bounds__(1024, 8) void bucket_gather(
    const uint2* __restrict__ pay, const int* __restrict__ gcur,
    const float* __restrict__ ws, float* __restrict__ out, int N)
{
    __shared__ float4 tabS[TABQ];        // scalar, viewed as float2[98*32]
    __shared__ float4 tabM[TABQ];        // msg table
    __shared__ float4 buf[BUFSZ];        // node-sorted padded payloads
    __shared__ int cntm[256];
    __shared__ int s_cnt[NPB], s_loff[NPB], s_cur[NPB];

    const int tid = threadIdx.x;
    const int b   = blockIdx.x;
    const int lo  = b << NPB_LOG;
    const int nn  = min(NPB, N - lo);
    const int bbeg = b * CAP;
    const int bsz  = min(gcur[b], CAP);

    {
        const float4* srcS = (const float4*)(ws + WS_ACS);
        const float4* srcM = (const float4*)(ws + WS_ACM);
        for (int i = tid; i < TABQ; i += 1024) { tabS[i] = srcS[i]; tabM[i] = srcM[i]; }
        if (tid < 256) cntm[tid] = ((const int*)(ws + WS_CNTM))[tid];
        if (tid < NPB) s_cnt[tid] = 0;
    }
    __syncthreads();

    // ---- Phase A: stage -> count -> wave0 scan (padded) -> insert+pad ----
    uint2 p[NP];
    int   loc[NP];
    #pragma unroll
    for (int i = 0; i < NP; ++i) {
        int idx = i * 1024 + tid;
        loc[i] = -1;
        if (idx < bsz) {
            p[i] = pay[bbeg + idx];
            loc[i] = (p[i].y >> 24) & (NPB - 1);
            atomicAdd(&s_cnt[loc[i]], 1);
        }
    }
    __syncthreads();
    if (tid < 64) {
        int cnt = s_cnt[tid];
        int pc  = (cnt + 1) & ~1;          // pair-padded size
        int incl = pc;
        #pragma unroll
        for (int off = 1; off < 64; off <<= 1) {
            int u = __shfl_up(incl, off, 64);
            if (tid >= off) incl += u;
        }
        s_loff[tid] = incl - pc;
        s_cur[tid]  = incl - pc;
    }
    __syncthreads();
    #pragma unroll
    for (int i = 0; i < NP; ++i) {
        if (loc[i] >= 0) {
            int pos = atomicAdd(&s_cur[loc[i]], 1);
            int q  = (p[i].y >> 16) & 255;
            int sm = cntm[q];
            int ss = q - sm;
            float x = __half2float(__ushort_as_half((unsigned short)(p[i].x & 0xFFFF)));
            float c = __half2float(__ushort_as_half((unsigned short)(p[i].x >> 16)));
            float s = __half2float(__ushort_as_half((unsigned short)(p[i].y & 0xFFFF)));
            buf[pos] = make_float4(x,
                __int_as_float(((ss << 5) << 16) | (sm << 4)), c, s);
        }
    }
    if (tid < NPB && (s_cnt[tid] & 1))
        buf[s_loff[tid] + s_cnt[tid]] =
            make_float4(0.f, __int_as_float(SENT_PK), 0.f, 0.f);
    __syncthreads();

    // ---- Phase B: 64 fused-mode tasks over 16 waves, guard-free ----
    const int wv   = tid >> 6;
    const int lane = tid & 63;
    const int k    = lane & 31;
    const int half = lane >> 5;
    const float2* t2 = (const float2*)tabS;
    const int jj = k >> 1, comp = k & 1;

    for (int i = 0; i < 4; ++i) {
        int node = wv + (i << 4);     // 0..63
        if (node >= nn) continue;
        int beg  = s_loff[node];
        int tmax = (s_cnt[node] + 1) >> 1;   // complete pairs (padded)
        float aS0 = 0.f, cS0 = 0.f, aS1 = 0.f, cS1 = 0.f;
        float aR0 = 0.f, bR0 = 0.f, aR1 = 0.f, bR1 = 0.f;
        int t = 0;
        for (; t + 2 <= tmax; t += 2) {
            float4 p0 = buf[beg + 2 * t + half];
            float4 p1 = buf[beg + 2 * t + 2 + half];
            unsigned k0 = (unsigned)__float_as_int(p0.y);
            unsigned k1 = (unsigned)__float_as_int(p1.y);
            float2 s0 = t2[(k0 >> 16) + k];
            float2 s1 = t2[(k1 >> 16) + k];
            float4 m0 = tabM[(k0 & 0xFFFFu) + jj];
            float4 m1 = tabM[(k1 & 0xFFFFu) + jj];
            aS0 = fmaf(s0.x, p0.x, aS0); cS0 += s0.y;
            aS1 = fmaf(s1.x, p1.x, aS1); cS1 += s1.y;
            float m00 = fmaf(m0.x, p0.x, m0.y);
            float m01 = fmaf(m0.z, p0.x, m0.w);
            float m10 = fmaf(m1.x, p1.x, m1.y);
            float m11 = fmaf(m1.z, p1.x, m1.w);
            // even k: m0*c + m1*s ; odd k: m1*c - m0*s
            float u0 = comp ? -p0.w : p0.z, w0 = comp ? p0.z : p0.w;
            float u1 = comp ? -p1.w : p1.z, w1 = comp ? p1.z : p1.w;
            aR0 = fmaf(m00, u0, aR0); bR0 = fmaf(m01, w0, bR0);
            aR1 = fmaf(m10, u1, aR1); bR1 = fmaf(m11, w1, bR1);
        }
        if (t < tmax) {
            float4 p0 = buf[beg + 2 * t + half];
            unsigned k0 = (unsigned)__float_as_int(p0.y);
            float2 s0 = t2[(k0 >> 16) + k];
            float4 m0 = tabM[(k0 & 0xFFFFu) + jj];
            aS0 = fmaf(s0.x, p0.x, aS0); cS0 += s0.y;
            float m00 = fmaf(m0.x, p0.x, m0.y);
            float m01 = fmaf(m0.z, p0.x, m0.w);
            float u0 = comp ? -p0.w : p0.z, w0 = comp ? p0.z : p0.w;
            aR0 = fmaf(m00, u0, aR0); bR0 = fmaf(m01, w0, bR0);
        }
        float accS = (aS0 + cS0) + (aS1 + cS1);
        float accR = (aR0 + bR0) + (aR1 + bR1);
        accS += __shfl_xor(accS, 32, 64);
        accR += __shfl_xor(accR, 32, 64);
        if (half == 0) {
            out[(size_t)(lo + node) * 32 + k] = accS;
            out[(size_t)N * 32 + (size_t)(lo + node) * 32 + k] = accR;
        }
    }
}

extern "C" void kernel_launch(void* const* d_in, const int* in_sizes, int n_in,
                              void* d_out, int out_size, void* d_ws, size_t ws_size,
                              hipStream_t stream) {
    const float* v      = (const float*)d_in[0];
    const float* rot    = (const float*)d_in[1];
    const int*   ei     = (const int*)d_in[2];
    const float* msg_w1 = (const float*)d_in[3];
    const float* msg_b1 = (const float*)d_in[4];
    const float* msg_w2 = (const float*)d_in[5];
    const float* msg_b2 = (const float*)d_in[6];
    const float* sc_w1  = (const float*)d_in[7];
    const float* sc_b1  = (const float*)d_in[8];
    const float* sc_w2  = (const float*)d_in[9];
    const float* sc_b2  = (const float*)d_in[10];

    const int E = in_sizes[0] / 2;    // v is [E,2]
    const int N = out_size / 64;      // out = N*32 scalars + N*32 rot floats
    const int NBK = (N + NPB - 1) >> NPB_LOG;   // 1563 for N=100000

    float* ws  = (float*)d_ws;
    float* out = (float*)d_out;

    int*   gcur = (int*)(ws + WS_GCUR);
    uint2* pay  = (uint2*)(ws + WS_PAY);

    const int epb = (E + SGRID - 1) / SGRID;    // 3125 for E=1.6M (<= ESTG)

    build_tables<<<dim3(NROW, 2), 96, 0, stream>>>(
        msg_w1, msg_b1, msg_w2, msg_b2, sc_w1, sc_b1, sc_w2, sc_b2,
        ws, gcur, NBK);
    bucket_scatter<<<SGRID, SCT, 0, stream>>>(
        v, rot, ei + E, ws, gcur, pay, E, NBK, epb);
    bucket_gather<<<NBK, 1024, 0, stream>>>(pay, gcur, ws, out, N);
}

// Round 17
// 87.266 us; speedup vs baseline: 1.7863x; 1.0258x over previous
//
#include <hip/hip_runtime.h>
#include <hip/hip_fp16.h>

#define H     96    // hidden width of both MLPs
#define NOUT  32    // outputs of both MLPs
#define NSEG  97    // H+1 piecewise-linear segments
#define SENTR 97    // all-zero sentinel table row
#define NROW  98
#define TABQ  1568  // float4 per table (98*16)

#define NPB_LOG 6
#define NPB     64    // nodes per bucket
#define MAXBK   1600  // max buckets (N <= 102400)
#define SGRID   512   // scatter grid (2 blocks/CU)
#define SCT     1024  // scatter threads (R17: 2x waves for latency hiding)
#define SWAVES  (SCT / 64)
#define EPTS    4     // max edges per thread (ceil(ceil(E/512)/1024)), E<=2.09M
#define ESTG    (EPTS * SCT)  // 4096 LDS staging slots
#define CAP     1536  // fixed bucket region stride (mean 1024, +16 sigma)
#define BUFSZ   (CAP + NPB + 8)   // padded gather buffer capacity
#define NP      2     // payloads staged per thread in bucket_gather

// prescaled sentinel pk: hi16 = 97*32 (t2 row 97), lo16 = 97*16 (tabM row 97)
#define SENT_PK ((3104 << 16) | 1552)

// ---- d_ws float-index layout -------------------------------------------
#define WS_ACS      256        // float2[98][32]  scalar (A, C+b2) [s][k], row 97 = 0
#define WS_ACM      6528       // float4[98][16]  msg (A0,C0,A1,C1) [s][j], row 97 = 0
#define WS_TSQ      13056      // float[256] merged breakpoints (+inf pad)
#define WS_CNTM     13312      // int[256]  cnt_m[q] = #msg-breakpoints < q-th
#define WS_GCUR     16384      // int[1600]  bucket cursors (counts after scatter)
#define WS_PAY      18048      // uint2[NBK*CAP + 1]  fixed-stride bucket payloads

// ---------------------------------------------------------------------------
// P12: FUSED breakpoints + tables (R15-proven). Grid (98, 2), 96 thr/block.
// Block (97,0) also writes merged ts_q + cntm; block (97,1) zeroes gcur.
// ---------------------------------------------------------------------------
__global__ __launch_bounds__(96) void build_tables(
    const float* __restrict__ msg_w1, const float* __restrict__ msg_b1,
    const float* __restrict__ msg_w2, const float* __restrict__ msg_b2,
    const float* __restrict__ sc_w1,  const float* __restrict__ sc_b1,
    const float* __restrict__ sc_w2,  const float* __restrict__ sc_b2,
    float* __restrict__ ws, int* __restrict__ gcur, int NBK)
{
    const int s    = blockIdx.x;   // 0..97
    const int mlp  = blockIdx.y;   // 0 = msg, 1 = sc
    const int tid  = threadIdx.x;  // 0..95
    const int part = tid >> 5;     // 0..2
    const int k    = tid & 31;

    __shared__ float tm[H], to[H];        // own / other breakpoints
    __shared__ int   rnk[H];
    __shared__ float pA[3][32], pC[3][32];
    __shared__ unsigned char ismsg[256];

    const float* w1  = mlp ? sc_w1 : msg_w1;
    const float* b1  = mlp ? sc_b1 : msg_b1;
    const float* w2  = mlp ? sc_w2 : msg_w2;
    const float* b2  = mlp ? sc_b2 : msg_b2;
    const float* w1o = mlp ? msg_w1 : sc_w1;
    const float* b1o = mlp ? msg_b1 : sc_b1;

    {
        float w  = w1[tid],  b  = b1[tid];
        float wo = w1o[tid], bo = b1o[tid];
        tm[tid] = (w  == 0.f) ? __builtin_inff() : (-b  / w);
        to[tid] = (wo == 0.f) ? __builtin_inff() : (-bo / wo);
    }
    __syncthreads();
    {
        float tj = tm[tid];
        int r = 0;
        for (int i = 0; i < H; ++i) {
            float ti = tm[i];
            r += (ti < tj) || (ti == tj && i < tid);
        }
        rnk[tid] = r;
    }
    __syncthreads();

    float A = 0.f, C = 0.f;
    if (s != SENTR) {
        const int j0 = part * 32;
        for (int j = j0; j < j0 + 32; ++j) {
            float w = w1[j], b = b1[j];
            int   r = rnk[j];
            bool active = (w > 0.f) ? (r < s)
                        : (w < 0.f) ? (r >= s)
                                    : (b > 0.f);
            if (active) {
                float wk = w2[j * NOUT + k];
                A = fmaf(w, wk, A);
                C = fmaf(b, wk, C);
            }
        }
    }
    pA[part][k] = A; pC[part][k] = C;
    __syncthreads();
    if (part == 0) {
        float Af = pA[0][k] + pA[1][k] + pA[2][k];
        float Cf = pC[0][k] + pC[1][k] + pC[2][k] + b2[k];
        if (s == SENTR) { Af = 0.f; Cf = 0.f; }
        if (mlp) {
            float* dst = ws + WS_ACS + 2 * (s * 32 + k);
            dst[0] = Af; dst[1] = Cf;
        } else {
            float* dst = ws + WS_ACM + 4 * (s * 16 + (k >> 1)) + 2 * (k & 1);
            dst[0] = Af; dst[1] = Cf;
        }
    }

    if (s == SENTR) {
        if (mlp == 1) {
            for (int i = tid; i < NBK; i += 96) gcur[i] = 0;
        } else {
            for (int i = tid; i < 256; i += 96) ismsg[i] = 0;
            __syncthreads();
            {   // msg element tid: merged rank (msg precedes sc on ties)
                float tj = tm[tid];
                int cross = 0;
                for (int i = 0; i < H; ++i) cross += (to[i] < tj);
                int q = rnk[tid] + cross;          // 0..191 bijective
                ws[WS_TSQ + q] = tj;
                ismsg[q] = 1;
            }
            {   // sc element tid
                float tj = to[tid];
                int r = 0;
                for (int i = 0; i < H; ++i) {
                    float ti = to[i];
                    r += (ti < tj) || (ti == tj && i < tid);
                }
                int cross = 0;
                for (int i = 0; i < H; ++i) cross += (tm[i] <= tj);
                ws[WS_TSQ + (r + cross)] = tj;
            }
            for (int i = 192 + tid; i < 256; i += 96)
                ws[WS_TSQ + i] = __builtin_inff();
            __syncthreads();
            if (tid == 0) {
                int acc = 0;
                int* cm = (int*)(ws + WS_CNTM);
                for (int i = 0; i < 256; ++i) { cm[i] = acc; acc += ismsg[i]; }
            }
        }
    }
}

// ---------------------------------------------------------------------------
// K3: bucket scatter into fixed-stride regions (pay[b*CAP + i]).
// R17: 1024 threads/block (32 waves/CU, 2x latency hiding), EPT = 4.
// payload: w0 = f16(x)|f16(c)<<16 ; w1 = f16(s)|q<<16|(col&63)<<24
// ---------------------------------------------------------------------------
__global__ __launch_bounds__(SCT) void bucket_scatter(
    const float* __restrict__ v, const float* __restrict__ rot,
    const int* __restrict__ col, const float* __restrict__ ws,
    int* __restrict__ gcur, uint2* __restrict__ pay, int E, int NBK, int epb)
{
    __shared__ float ts_q[256];
    __shared__ int   lcnt[MAXBK];     // counts -> reused as insert cursor
    __shared__ int   lofs[MAXBK];     // local exclusive offsets
    __shared__ int   gdelta[MAXBK];   // b*CAP + global_base - local_offset
    __shared__ int   wsum[SWAVES], woff[SWAVES];
    __shared__ uint2 stage[ESTG];     // 32 KB
    __shared__ int   gaddr[ESTG];     // 16 KB

    const int tid  = threadIdx.x;
    const int lane = tid & 63;
    const int wv   = tid >> 6;
    for (int i = tid; i < 256; i += SCT) ts_q[i] = ws[WS_TSQ + i];
    for (int i = tid; i < MAXBK; i += SCT) lcnt[i] = 0;
    __syncthreads();

    const int e0 = blockIdx.x * epb;
    const int e1 = min(e0 + epb, E);
    const int DUMP = NBK * CAP;       // spare slot for (unreachable) overflow

    // phase 1: load + compute payloads into registers + count
    int   col_r[EPTS];
    uint2 pld[EPTS];
    #pragma unroll
    for (int i = 0; i < EPTS; ++i) {
        int e = e0 + i * SCT + tid;
        int c = (e < e1) ? col[e] : -1;
        col_r[i] = c;
        if (c >= 0) {
            float2 vv = *(const float2*)(v + 2 * (size_t)e);
            float4 r  = *(const float4*)(rot + 4 * (size_t)e);
            float  x  = sqrtf(vv.x * vv.x + vv.y * vv.y);
            int q = 0;
            #pragma unroll
            for (int st = 128; st > 0; st >>= 1)
                if (ts_q[q + st - 1] < x) q += st;
            unsigned hx = __half_as_ushort(__float2half(x));
            unsigned hc = __half_as_ushort(__float2half(r.x));
            unsigned hs = __half_as_ushort(__float2half(r.z));
            pld[i] = make_uint2(hx | (hc << 16),
                hs | ((unsigned)q << 16) | ((unsigned)(c & (NPB - 1)) << 24));
            atomicAdd(&lcnt[c >> NPB_LOG], 1);
        }
    }
    __syncthreads();

    // phase 2: exclusive scan over MAXBK via wave-shfl (2 barriers total)
    int b0 = tid * 4;
    int c0 = (b0 + 0 < MAXBK) ? lcnt[b0 + 0] : 0;
    int c1 = (b0 + 1 < MAXBK) ? lcnt[b0 + 1] : 0;
    int c2 = (b0 + 2 < MAXBK) ? lcnt[b0 + 2] : 0;
    int c3 = (b0 + 3 < MAXBK) ? lcnt[b0 + 3] : 0;
    int mysum = c0 + c1 + c2 + c3;
    int incl  = mysum;
    #pragma unroll
    for (int off = 1; off < 64; off <<= 1) {
        int u = __shfl_up(incl, off, 64);
        if (lane >= off) incl += u;
    }
    if (lane == 63) wsum[wv] = incl;
    __syncthreads();
    if (wv == 0 && lane < SWAVES) {
        int vv2 = wsum[lane];
        int s2  = vv2;
        #pragma unroll
        for (int off = 1; off < SWAVES; off <<= 1) {
            int u = __shfl_up(s2, off, SWAVES);
            if (lane >= off) s2 += u;
        }
        woff[lane] = s2 - vv2;   // exclusive across waves
    }
    __syncthreads();
    {
        int run = (incl - mysum) + woff[wv];
        if (b0 + 0 < MAXBK) { lofs[b0 + 0] = run; run += c0; }
        if (b0 + 1 < MAXBK) { lofs[b0 + 1] = run; run += c1; }
        if (b0 + 2 < MAXBK) { lofs[b0 + 2] = run; run += c2; }
        if (b0 + 3 < MAXBK) { lofs[b0 + 3] = run; run += c3; }
    }
    __syncthreads();

    // phase 3: per-bucket global base from fixed-stride region
    for (int b = tid; b < NBK; b += SCT) {
        int c = lcnt[b];
        if (c) {
            int g = atomicAdd(&gcur[b], c);
            gdelta[b] = b * CAP + g - lofs[b];
        }
        lcnt[b] = lofs[b];            // reuse as insert cursor
    }
    __syncthreads();

    // phase 4: pure LDS insert (payloads already in registers)
    #pragma unroll
    for (int i = 0; i < EPTS; ++i) {
        int c = col_r[i];
        if (c < 0) continue;
        int b    = c >> NPB_LOG;
        int lpos = atomicAdd(&lcnt[b], 1);
        int abspos = gdelta[b] + lpos;
        stage[lpos] = pld[i];
        gaddr[lpos] = (abspos - b * CAP < CAP) ? abspos : DUMP;
    }
    __syncthreads();

    // phase 5: streamed write-out (consecutive threads -> consecutive addrs)
    const int nB = e1 - e0;
    for (int i = tid; i < nB; i += SCT)
        pay[gaddr[i]] = stage[i];
}

// ---------------------------------------------------------------------------
// K4+gather fused (R16-proven, byte-identical): block = bucket (64 nodes),
// 1024 threads = 16 waves. One task = one node, scalar AND rot in one pass.
// ---------------------------------------------------------------------------
__global__ __launch_bounds__(1024, 8) void bucket_gather(
    const uint2* __restrict__ pay, const int* __restrict__ gcur,
    const float* __restrict__ ws, float* __restrict__ out, int N)
{
    __shared__ float4 tabS[TABQ];        // scalar, viewed as float2[98*32]
    __shared__ float4 tabM[TABQ];        // msg table
    __shared__ float4 buf[BUFSZ];        // node-sorted padded payloads
    __shared__ int cntm[256];
    __shared__ int s_cnt[NPB], s_loff[NPB], s_cur[NPB];

    const int tid = threadIdx.x;
    const int b   = blockIdx.x;
    const int lo  = b << NPB_LOG;
    const int nn  = min(NPB, N - lo);
    const int bbeg = b * CAP;
    const int bsz  = min(gcur[b], CAP);

    {
        const float4* srcS = (const float4*)(ws + WS_ACS);
        const float4* srcM = (const float4*)(ws + WS_ACM);
        for (int i = tid; i < TABQ; i += 1024) { tabS[i] = srcS[i]; tabM[i] = srcM[i]; }
        if (tid < 256) cntm[tid] = ((const int*)(ws + WS_CNTM))[tid];
        if (tid < NPB) s_cnt[tid] = 0;
    }
    __syncthreads();

    // ---- Phase A: stage -> count -> wave0 scan (padded) -> insert+pad ----
    uint2 p[NP];
    int   loc[NP];
    #pragma unroll
    for (int i = 0; i < NP; ++i) {
        int idx = i * 1024 + tid;
        loc[i] = -1;
        if (idx < bsz) {
            p[i] = pay[bbeg + idx];
            loc[i] = (p[i].y >> 24) & (NPB - 1);
            atomicAdd(&s_cnt[loc[i]], 1);
        }
    }
    __syncthreads();
    if (tid < 64) {
        int cnt = s_cnt[tid];
        int pc  = (cnt + 1) & ~1;          // pair-padded size
        int incl = pc;
        #pragma unroll
        for (int off = 1; off < 64; off <<= 1) {
            int u = __shfl_up(incl, off, 64);
            if (tid >= off) incl += u;
        }
        s_loff[tid] = incl - pc;
        s_cur[tid]  = incl - pc;
    }
    __syncthreads();
    #pragma unroll
    for (int i = 0; i < NP; ++i) {
        if (loc[i] >= 0) {
            int pos = atomicAdd(&s_cur[loc[i]], 1);
            int q  = (p[i].y >> 16) & 255;
            int sm = cntm[q];
            int ss = q - sm;
            float x = __half2float(__ushort_as_half((unsigned short)(p[i].x & 0xFFFF)));
            float c = __half2float(__ushort_as_half((unsigned short)(p[i].x >> 16)));
            float s = __half2float(__ushort_as_half((unsigned short)(p[i].y & 0xFFFF)));
            buf[pos] = make_float4(x,
                __int_as_float(((ss << 5) << 16) | (sm << 4)), c, s);
        }
    }
    if (tid < NPB && (s_cnt[tid] & 1))
        buf[s_loff[tid] + s_cnt[tid]] =
            make_float4(0.f, __int_as_float(SENT_PK), 0.f, 0.f);
    __syncthreads();

    // ---- Phase B: 64 fused-mode tasks over 16 waves, guard-free ----
    const int wv   = tid >> 6;
    const int lane = tid & 63;
    const int k    = lane & 31;
    const int half = lane >> 5;
    const float2* t2 = (const float2*)tabS;
    const int jj = k >> 1, comp = k & 1;

    for (int i = 0; i < 4; ++i) {
        int node = wv + (i << 4);     // 0..63
        if (node >= nn) continue;
        int beg  = s_loff[node];
        int tmax = (s_cnt[node] + 1) >> 1;   // complete pairs (padded)
        float aS0 = 0.f, cS0 = 0.f, aS1 = 0.f, cS1 = 0.f;
        float aR0 = 0.f, bR0 = 0.f, aR1 = 0.f, bR1 = 0.f;
        int t = 0;
        for (; t + 2 <= tmax; t += 2) {
            float4 p0 = buf[beg + 2 * t + half];
            float4 p1 = buf[beg + 2 * t + 2 + half];
            unsigned k0 = (unsigned)__float_as_int(p0.y);
            unsigned k1 = (unsigned)__float_as_int(p1.y);
            float2 s0 = t2[(k0 >> 16) + k];
            float2 s1 = t2[(k1 >> 16) + k];
            float4 m0 = tabM[(k0 & 0xFFFFu) + jj];
            float4 m1 = tabM[(k1 & 0xFFFFu) + jj];
            aS0 = fmaf(s0.x, p0.x, aS0); cS0 += s0.y;
            aS1 = fmaf(s1.x, p1.x, aS1); cS1 += s1.y;
            float m00 = fmaf(m0.x, p0.x, m0.y);
            float m01 = fmaf(m0.z, p0.x, m0.w);
            float m10 = fmaf(m1.x, p1.x, m1.y);
            float m11 = fmaf(m1.z, p1.x, m1.w);
            // even k: m0*c + m1*s ; odd k: m1*c - m0*s
            float u0 = comp ? -p0.w : p0.z, w0 = comp ? p0.z : p0.w;
            float u1 = comp ? -p1.w : p1.z, w1 = comp ? p1.z : p1.w;
            aR0 = fmaf(m00, u0, aR0); bR0 = fmaf(m01, w0, bR0);
            aR1 = fmaf(m10, u1, aR1); bR1 = fmaf(m11, w1, bR1);
        }
        if (t < tmax) {
            float4 p0 = buf[beg + 2 * t + half];
            unsigned k0 = (unsigned)__float_as_int(p0.y);
            float2 s0 = t2[(k0 >> 16) + k];
            float4 m0 = tabM[(k0 & 0xFFFFu) + jj];
            aS0 = fmaf(s0.x, p0.x, aS0); cS0 += s0.y;
            float m00 = fmaf(m0.x, p0.x, m0.y);
            float m01 = fmaf(m0.z, p0.x, m0.w);
            float u0 = comp ? -p0.w : p0.z, w0 = comp ? p0.z : p0.w;
            aR0 = fmaf(m00, u0, aR0); bR0 = fmaf(m01, w0, bR0);
        }
        float accS = (aS0 + cS0) + (aS1 + cS1);
        float accR = (aR0 + bR0) + (aR1 + bR1);
        accS += __shfl_xor(accS, 32, 64);
        accR += __shfl_xor(accR, 32, 64);
        if (half == 0) {
            out[(size_t)(lo + node) * 32 + k] = accS;
            out[(size_t)N * 32 + (size_t)(lo + node) * 32 + k] = accR;
        }
    }
}

extern "C" void kernel_launch(void* const* d_in, const int* in_sizes, int n_in,
                              void* d_out, int out_size, void* d_ws, size_t ws_size,
                              hipStream_t stream) {
    const float* v      = (const float*)d_in[0];
    const float* rot    = (const float*)d_in[1];
    const int*   ei     = (const int*)d_in[2];
    const float* msg_w1 = (const float*)d_in[3];
    const float* msg_b1 = (const float*)d_in[4];
    const float* msg_w2 = (const float*)d_in[5];
    const float* msg_b2 = (const float*)d_in[6];
    const float* sc_w1  = (const float*)d_in[7];
    const float* sc_b1  = (const float*)d_in[8];
    const float* sc_w2  = (const float*)d_in[9];
    const float* sc_b2  = (const float*)d_in[10];

    const int E = in_sizes[0] / 2;    // v is [E,2]
    const int N = out_size / 64;      // out = N*32 scalars + N*32 rot floats
    const int NBK = (N + NPB - 1) >> NPB_LOG;   // 1563 for N=100000

    float* ws  = (float*)d_ws;
    float* out = (float*)d_out;

    int*   gcur = (int*)(ws + WS_GCUR);
    uint2* pay  = (uint2*)(ws + WS_PAY);

    const int epb = (E + SGRID - 1) / SGRID;    // 3125 for E=1.6M (<= ESTG)

    build_tables<<<dim3(NROW, 2), 96, 0, stream>>>(
        msg_w1, msg_b1, msg_w2, msg_b2, sc_w1, sc_b1, sc_w2, sc_b2,
        ws, gcur, NBK);
    bucket_scatter<<<SGRID, SCT, 0, stream>>>(
        v, rot, ei + E, ws, gcur, pay, E, NBK, epb);
    bucket_gather<<<NBK, 1024, 0, stream>>>(pay, gcur, ws, out, N);
}